// Round 2
// baseline (45052.530 us; speedup 1.0000x reference)
//
#include <hip/hip_runtime.h>
#include <math.h>

#define BATCH   16
#define SEQ     768
#define DMODEL  512
#define DSTATE  128
#define DINNER  1024
#define NHEADS  16
#define HEADDIM 64
#define CONVDIM 1280            // DINNER + 2*DSTATE
#define DINPROJ 2320            // 2*DINNER + 2*DSTATE + NHEADS
#define NLAYER  28
#define VOCABSZ 256
#define NROWS   (BATCH*SEQ)     // 12288
#define EPSV    1e-5f
#define NCH     8               // chunks per sequence
#define CH      96              // SEQ / NCH
#define STATESZ (HEADDIM*DSTATE) // 8192 floats per (b,h,chunk)

__device__ __forceinline__ float siluf(float v) { return v / (1.f + expf(-v)); }

// ---------------- embedding gather ----------------
__global__ __launch_bounds__(256) void embed_kernel(const int* __restrict__ tok,
    const float* __restrict__ emb, float* __restrict__ hid) {
  int i = blockIdx.x * 256 + threadIdx.x;
  if (i >= NROWS * DMODEL) return;
  int r = i >> 9;               // / DMODEL
  int d = i & (DMODEL - 1);
  hid[i] = emb[(size_t)tok[r] * DMODEL + d];
}

// ---------------- residual add + RMSNorm (512 cols) ----------------
__global__ __launch_bounds__(128) void prenorm_kernel(const float* __restrict__ h,
    float* __restrict__ res, const float* __restrict__ w, float* __restrict__ xn) {
  int row = blockIdx.x;
  int tid = threadIdx.x;        // 128 threads, one float4 each (512 cols)
  const float4* h4 = (const float4*)(h + (size_t)row * DMODEL);
  float4* r4 = (float4*)(res + (size_t)row * DMODEL);
  float4 v = r4[tid];
  float4 a = h4[tid];
  v.x += a.x; v.y += a.y; v.z += a.z; v.w += a.w;
  r4[tid] = v;
  float ss = v.x * v.x + v.y * v.y + v.z * v.z + v.w * v.w;
  #pragma unroll
  for (int o = 32; o > 0; o >>= 1) ss += __shfl_down(ss, o);
  __shared__ float wred[2];
  if ((tid & 63) == 0) wred[tid >> 6] = ss;
  __syncthreads();
  float tot = wred[0] + wred[1];
  float scale = rsqrtf(tot / (float)DMODEL + EPSV);
  const float4* w4 = (const float4*)w;
  float4 wv = w4[tid];
  float4 o4;
  o4.x = v.x * scale * wv.x; o4.y = v.y * scale * wv.y;
  o4.z = v.z * scale * wv.z; o4.w = v.w * scale * wv.w;
  ((float4*)(xn + (size_t)row * DMODEL))[tid] = o4;
}

// ---------------- generic fp32 GEMM: C[M,N] = A[M,K] * B[N,K]^T ----------------
#define GBM 64
#define GBN 64
#define GBK 16
__global__ __launch_bounds__(256) void gemm_bt(const float* __restrict__ A,
    const float* __restrict__ B, float* __restrict__ C, int M, int N, int K) {
  __shared__ float As[GBK][GBM + 4];
  __shared__ float Bs[GBK][GBN + 4];
  int tid = threadIdx.x;
  int m0 = blockIdx.y * GBM;
  int n0 = blockIdx.x * GBN;
  int tx = tid & 15, ty = tid >> 4;
  int lrow = tid >> 2;            // 0..63
  int lk = (tid & 3) * 4;         // 0,4,8,12
  float acc[4][4] = {};
  for (int k0 = 0; k0 < K; k0 += GBK) {
    float4 av = *(const float4*)(A + (size_t)(m0 + lrow) * K + k0 + lk);
    int bn = n0 + lrow;
    float4 bv = make_float4(0.f, 0.f, 0.f, 0.f);
    if (bn < N) bv = *(const float4*)(B + (size_t)bn * K + k0 + lk);
    As[lk + 0][lrow] = av.x; As[lk + 1][lrow] = av.y;
    As[lk + 2][lrow] = av.z; As[lk + 3][lrow] = av.w;
    Bs[lk + 0][lrow] = bv.x; Bs[lk + 1][lrow] = bv.y;
    Bs[lk + 2][lrow] = bv.z; Bs[lk + 3][lrow] = bv.w;
    __syncthreads();
    #pragma unroll
    for (int k = 0; k < GBK; ++k) {
      float4 a = *(const float4*)&As[k][ty * 4];
      float4 bq = *(const float4*)&Bs[k][tx * 4];
      float avx[4] = {a.x, a.y, a.z, a.w};
      float bvx[4] = {bq.x, bq.y, bq.z, bq.w};
      #pragma unroll
      for (int i = 0; i < 4; ++i)
        #pragma unroll
        for (int j = 0; j < 4; ++j)
          acc[i][j] += avx[i] * bvx[j];
    }
    __syncthreads();
  }
  #pragma unroll
  for (int i = 0; i < 4; ++i) {
    int m = m0 + ty * 4 + i;
    int n = n0 + tx * 4;
    if (n < N)
      *(float4*)(C + (size_t)m * N + n) =
          make_float4(acc[i][0], acc[i][1], acc[i][2], acc[i][3]);
  }
}

// ---------------- dt = softplus(raw + bias); dA = exp(dt * A) ----------------
__global__ __launch_bounds__(256) void dt_kernel(const float* __restrict__ zx,
    const float* __restrict__ dt_bias, const float* __restrict__ A_log,
    float* __restrict__ dt, float* __restrict__ dA) {
  int i = blockIdx.x * 256 + threadIdx.x;
  if (i >= NROWS * NHEADS) return;
  int h = i & (NHEADS - 1);
  int row = i >> 4;
  float v = zx[(size_t)row * DINPROJ + (DINNER + CONVDIM) + h] + dt_bias[h];
  float sp = fmaxf(v, 0.f) + log1pf(expf(-fabsf(v)));
  float Ah = -expf(A_log[h]);
  dt[i] = sp;
  dA[i] = expf(sp * Ah);
}

// ---------------- causal conv (width 4) + silu ----------------
__global__ __launch_bounds__(256) void conv_kernel(const float* __restrict__ zx,
    const float* __restrict__ cw, const float* __restrict__ cb, float* __restrict__ out) {
  int c = blockIdx.x * 256 + threadIdx.x;      // 0..1279
  int bl = blockIdx.y;                         // 0..NROWS-1
  int t = bl % SEQ;
  float acc = cb[c];
  #pragma unroll
  for (int k = 0; k < 4; ++k) {
    int tt = t + k - 3;
    if (tt >= 0)
      acc += zx[(size_t)(bl + k - 3) * DINPROJ + DINNER + c] * cw[c * 4 + k];
  }
  out[(size_t)bl * CONVDIM + c] = siluf(acc);
}

// ---------------- chunked SSD scan, pass 1: local scan from zero state ----------------
// grid (NCH, BATCH*NHEADS); writes y_local (+D*x), end-state S(c), chunk dA-product P(c)
__global__ __launch_bounds__(256) void scan_local_kernel(const float* __restrict__ conv,
    const float* __restrict__ dtb, const float* __restrict__ dAb,
    const float* __restrict__ Dp, float* __restrict__ y,
    float* __restrict__ state, float* __restrict__ chunkprod) {
  int c = blockIdx.x;
  int bh = blockIdx.y;
  int b = bh >> 4, h = bh & 15;
  int tid = threadIdx.x;
  int s = tid >> 6;               // wave id: n-slice [32s, 32s+32)
  int p = tid & 63;               // lane = headdim index
  float hs[32];
  #pragma unroll
  for (int j = 0; j < 32; ++j) hs[j] = 0.f;
  float Dh = Dp[h];
  float prod = 1.f;
  __shared__ float yred[8][4][64];
  const int nbase = DINNER + s * 32;
  const int tstart = c * CH;
  for (int t0 = 0; t0 < CH; t0 += 8) {
    #pragma unroll 1
    for (int tc = 0; tc < 8; ++tc) {
      int t = tstart + t0 + tc;
      size_t rbase = (size_t)(b * SEQ + t) * CONVDIM;
      float x = conv[rbase + h * HEADDIM + p];
      int dti = (b * SEQ + t) * NHEADS + h;
      float dtv = dtb[dti];
      float dAv = dAb[dti];
      float dtx = dtv * x;
      prod *= dAv;
      const float4* Bp = (const float4*)(conv + rbase + nbase);
      const float4* Cp = (const float4*)(conv + rbase + nbase + DSTATE);
      float y0 = 0.f, y1 = 0.f, y2 = 0.f, y3 = 0.f;
      #pragma unroll
      for (int q = 0; q < 8; ++q) {
        float4 Bv = Bp[q];
        float4 Cv = Cp[q];
        hs[q * 4 + 0] = dAv * hs[q * 4 + 0] + dtx * Bv.x; y0 += hs[q * 4 + 0] * Cv.x;
        hs[q * 4 + 1] = dAv * hs[q * 4 + 1] + dtx * Bv.y; y1 += hs[q * 4 + 1] * Cv.y;
        hs[q * 4 + 2] = dAv * hs[q * 4 + 2] + dtx * Bv.z; y2 += hs[q * 4 + 2] * Cv.z;
        hs[q * 4 + 3] = dAv * hs[q * 4 + 3] + dtx * Bv.w; y3 += hs[q * 4 + 3] * Cv.w;
      }
      float yp = (y0 + y1) + (y2 + y3);
      if (s == 0) yp += Dh * x;
      yred[tc][s][p] = yp;
    }
    __syncthreads();
    for (int i = tid; i < 512; i += 256) {
      int tc = i >> 6, pp = i & 63;
      float v = yred[tc][0][pp] + yred[tc][1][pp] + yred[tc][2][pp] + yred[tc][3][pp];
      y[((size_t)(b * SEQ + tstart + t0 + tc) * NHEADS + h) * HEADDIM + pp] = v;
    }
    __syncthreads();
  }
  // write end-state, layout [n][p] (n-major) for coalesced p-contiguous access
  size_t sbase = ((size_t)bh * NCH + c) * STATESZ;
  #pragma unroll
  for (int j = 0; j < 32; ++j)
    state[sbase + (size_t)(s * 32 + j) * HEADDIM + p] = hs[j];
  if (tid == 0) chunkprod[bh * NCH + c] = prod;
}

// ---------------- pass 2: sequential combine across chunks (in place) ----------------
// slot c is transformed from S(c) (local end-state) to H_in(c) (incoming state)
__global__ __launch_bounds__(256) void state_combine_kernel(float* __restrict__ state,
    const float* __restrict__ chunkprod) {
  int bh = blockIdx.x;
  int tid = threadIdx.x;          // each thread owns 32 consecutive state elems
  float hin[32];
  #pragma unroll
  for (int j = 0; j < 32; ++j) hin[j] = 0.f;
  size_t base = (size_t)bh * NCH * STATESZ + (size_t)tid * 32;
  for (int c = 0; c < NCH; ++c) {
    float4* sp = (float4*)(state + base + (size_t)c * STATESZ);
    float S[32];
    #pragma unroll
    for (int q = 0; q < 8; ++q) {
      float4 v = sp[q];
      S[q * 4 + 0] = v.x; S[q * 4 + 1] = v.y; S[q * 4 + 2] = v.z; S[q * 4 + 3] = v.w;
    }
    float P = chunkprod[bh * NCH + c];
    #pragma unroll
    for (int q = 0; q < 8; ++q)
      sp[q] = make_float4(hin[q * 4 + 0], hin[q * 4 + 1], hin[q * 4 + 2], hin[q * 4 + 3]);
    #pragma unroll
    for (int j = 0; j < 32; ++j) hin[j] = P * hin[j] + S[j];
  }
}

// ---------------- pass 3: y[t] += cumA_incl[t] * (C_t . H_in) ----------------
// grid (NCH-1, BATCH*NHEADS); chunk 0 has H_in = 0
__global__ __launch_bounds__(256) void ycorr_kernel(const float* __restrict__ conv,
    const float* __restrict__ dAb, const float* __restrict__ state,
    float* __restrict__ y) {
  int c = blockIdx.x + 1;
  int bh = blockIdx.y;
  int b = bh >> 4, h = bh & 15;
  int tid = threadIdx.x;
  __shared__ float hlds[STATESZ];   // [n][p] layout, bank = p%32 -> conflict-free
  __shared__ float cA[CH];
  const float4* sp = (const float4*)(state + ((size_t)bh * NCH + c) * STATESZ);
  float4* hl4 = (float4*)hlds;
  for (int i = tid; i < STATESZ / 4; i += 256) hl4[i] = sp[i];
  const int tstart = c * CH;
  if (tid < CH) cA[tid] = dAb[(b * SEQ + tstart + tid) * NHEADS + h];
  __syncthreads();
  // inclusive product scan over cA (Hillis-Steele)
  for (int off = 1; off < CH; off <<= 1) {
    float tmp = 1.f;
    if (tid < CH && tid >= off) tmp = cA[tid - off];
    __syncthreads();
    if (tid < CH) cA[tid] *= tmp;
    __syncthreads();
  }
  int s = tid >> 6, p = tid & 63;
  for (int tt = s; tt < CH; tt += 4) {
    int t = tstart + tt;
    const float4* Cp = (const float4*)(conv + (size_t)(b * SEQ + t) * CONVDIM + DINNER + DSTATE);
    float acc = 0.f;
    #pragma unroll
    for (int nq = 0; nq < DSTATE / 4; ++nq) {
      float4 Cv = Cp[nq];
      acc += Cv.x * hlds[(nq * 4 + 0) * HEADDIM + p];
      acc += Cv.y * hlds[(nq * 4 + 1) * HEADDIM + p];
      acc += Cv.z * hlds[(nq * 4 + 2) * HEADDIM + p];
      acc += Cv.w * hlds[(nq * 4 + 3) * HEADDIM + p];
    }
    size_t yi = ((size_t)(b * SEQ + t) * NHEADS + h) * HEADDIM + p;
    y[yi] += cA[tt] * acc;
  }
}

// ---------------- gated RMSNorm over 1024 (in place: out == y) ----------------
__global__ __launch_bounds__(256) void gated_norm_kernel(float* __restrict__ y,
    const float* __restrict__ zx, const float* __restrict__ gw) {
  int row = blockIdx.x;
  int tid = threadIdx.x;          // 256 threads, one float4 each (1024 cols)
  float4* y4 = (float4*)(y + (size_t)row * DINNER);
  const float4* z4 = (const float4*)(zx + (size_t)row * DINPROJ);
  float4 yv = y4[tid];
  float4 zv = z4[tid];
  float4 g;
  g.x = yv.x * siluf(zv.x); g.y = yv.y * siluf(zv.y);
  g.z = yv.z * siluf(zv.z); g.w = yv.w * siluf(zv.w);
  float ss = g.x * g.x + g.y * g.y + g.z * g.z + g.w * g.w;
  #pragma unroll
  for (int o = 32; o > 0; o >>= 1) ss += __shfl_down(ss, o);
  __shared__ float red[4];
  if ((tid & 63) == 0) red[tid >> 6] = ss;
  __syncthreads();
  float tot = red[0] + red[1] + red[2] + red[3];
  float scale = rsqrtf(tot / (float)DINNER + EPSV);
  const float4* g4 = (const float4*)gw;
  float4 wv = g4[tid];
  float4 o4;
  o4.x = g.x * scale * wv.x; o4.y = g.y * scale * wv.y;
  o4.z = g.z * scale * wv.z; o4.w = g.w * scale * wv.w;
  y4[tid] = o4;
}

// ---------------- per-row loss: lse - logit[target] ----------------
__global__ __launch_bounds__(256) void rowloss_kernel(const float* __restrict__ logits,
    const int* __restrict__ targets, float* __restrict__ rl) {
  int row = blockIdx.x * 4 + (threadIdx.x >> 6);
  int lane = threadIdx.x & 63;
  const float* lr = logits + (size_t)row * VOCABSZ;
  float4 v = ((const float4*)lr)[lane];
  float mx = fmaxf(fmaxf(v.x, v.y), fmaxf(v.z, v.w));
  #pragma unroll
  for (int o = 32; o > 0; o >>= 1) mx = fmaxf(mx, __shfl_down(mx, o));
  mx = __shfl(mx, 0);
  float e = expf(v.x - mx) + expf(v.y - mx) + expf(v.z - mx) + expf(v.w - mx);
  #pragma unroll
  for (int o = 32; o > 0; o >>= 1) e += __shfl_down(e, o);
  if (lane == 0) {
    float lse = logf(e) + mx;
    rl[row] = lse - lr[targets[row]];
  }
}

__global__ __launch_bounds__(256) void loss_reduce_kernel(const float* __restrict__ rl,
    float* __restrict__ out) {
  int tid = threadIdx.x;
  float ssum = 0.f;
  for (int i = tid; i < NROWS; i += 256) ssum += rl[i];
  #pragma unroll
  for (int o = 32; o > 0; o >>= 1) ssum += __shfl_down(ssum, o);
  __shared__ float red[4];
  if ((tid & 63) == 0) red[tid >> 6] = ssum;
  __syncthreads();
  if (tid == 0) out[0] = (red[0] + red[1] + red[2] + red[3]) / (float)NROWS;
}

extern "C" void kernel_launch(void* const* d_in, const int* in_sizes, int n_in,
                              void* d_out, int out_size, void* d_ws, size_t ws_size,
                              hipStream_t stream) {
  const int*   tokens       = (const int*)d_in[0];
  const int*   targets      = (const int*)d_in[1];
  const float* embedding    = (const float*)d_in[2];
  const float* in_proj_w    = (const float*)d_in[3];
  const float* conv_w       = (const float*)d_in[4];
  const float* conv_b       = (const float*)d_in[5];
  const float* dt_bias      = (const float*)d_in[6];
  const float* A_log        = (const float*)d_in[7];
  const float* Dp           = (const float*)d_in[8];
  const float* gnorm_w      = (const float*)d_in[9];
  const float* out_proj_w   = (const float*)d_in[10];
  const float* block_norm_w = (const float*)d_in[11];
  const float* norm_f_w     = (const float*)d_in[12];
  float* out = (float*)d_out;

  float* ws = (float*)d_ws;
  size_t off = 0;
  float* hidden   = ws + off; off += (size_t)NROWS * DMODEL;
  float* residual = ws + off; off += (size_t)NROWS * DMODEL;
  float* zx       = ws + off; off += (size_t)NROWS * DINPROJ;
  float* convo    = ws + off; off += (size_t)NROWS * CONVDIM;
  float* dtb      = ws + off; off += (size_t)NROWS * NHEADS;
  float* dAb      = ws + off; off += (size_t)NROWS * NHEADS;
  float* ybuf     = ws + off; off += (size_t)NROWS * DINNER;
  float* cprod    = ws + off; off += (size_t)BATCH * NHEADS * NCH;
  float* rowloss  = ws + off; off += NROWS;
  // union region: xn (6.29M floats) and state (16.78M floats) have disjoint
  // live ranges within a layer (xn: prenorm->gemm1; state: scan_local->ycorr)
  float* xn       = ws + off;
  float* state    = ws + off; off += (size_t)BATCH * NHEADS * NCH * STATESZ;

  hipMemsetAsync(residual, 0, (size_t)NROWS * DMODEL * sizeof(float), stream);
  embed_kernel<<<NROWS * DMODEL / 256, 256, 0, stream>>>(tokens, embedding, hidden);

  for (int l = 0; l < NLAYER; ++l) {
    const float* ipw = in_proj_w + (size_t)l * DINPROJ * DMODEL;
    const float* cw  = conv_w + (size_t)l * CONVDIM * 4;
    const float* cb  = conv_b + (size_t)l * CONVDIM;
    const float* dtbias_l = dt_bias + (size_t)l * NHEADS;
    const float* alog_l   = A_log + (size_t)l * NHEADS;
    const float* D_l      = Dp + (size_t)l * NHEADS;
    const float* gw  = gnorm_w + (size_t)l * DINNER;
    const float* opw = out_proj_w + (size_t)l * DMODEL * DINNER;
    const float* bnw = block_norm_w + (size_t)l * DMODEL;

    prenorm_kernel<<<NROWS, 128, 0, stream>>>(hidden, residual, bnw, xn);
    dim3 g1((DINPROJ + GBN - 1) / GBN, NROWS / GBM);
    gemm_bt<<<g1, 256, 0, stream>>>(xn, ipw, zx, NROWS, DINPROJ, DMODEL);
    dt_kernel<<<(NROWS * NHEADS) / 256, 256, 0, stream>>>(zx, dtbias_l, alog_l, dtb, dAb);
    conv_kernel<<<dim3(CONVDIM / 256, NROWS), 256, 0, stream>>>(zx, cw, cb, convo);
    scan_local_kernel<<<dim3(NCH, BATCH * NHEADS), 256, 0, stream>>>(
        convo, dtb, dAb, D_l, ybuf, state, cprod);
    state_combine_kernel<<<BATCH * NHEADS, 256, 0, stream>>>(state, cprod);
    ycorr_kernel<<<dim3(NCH - 1, BATCH * NHEADS), 256, 0, stream>>>(
        convo, dAb, state, ybuf);
    gated_norm_kernel<<<NROWS, 256, 0, stream>>>(ybuf, zx, gw);
    dim3 g2(DMODEL / GBN, NROWS / GBM);
    gemm_bt<<<g2, 256, 0, stream>>>(ybuf, opw, hidden, NROWS, DMODEL, DINNER);
  }

  prenorm_kernel<<<NROWS, 128, 0, stream>>>(hidden, residual, norm_f_w, xn);
  dim3 g3(VOCABSZ / GBN, NROWS / GBM);
  gemm_bt<<<g3, 256, 0, stream>>>(xn, embedding, out, NROWS, VOCABSZ, DMODEL);
  rowloss_kernel<<<NROWS / 4, 256, 0, stream>>>(out, targets, rowloss);
  loss_reduce_kernel<<<1, 256, 0, stream>>>(rowloss, out + (size_t)(out_size - 1));
}

// Round 3
// 30633.032 us; speedup vs baseline: 1.4707x; 1.4707x over previous
//
#include <hip/hip_runtime.h>
#include <hip/hip_bf16.h>
#include <math.h>

#define BATCH   16
#define SEQ     768
#define DMODEL  512
#define DSTATE  128
#define DINNER  1024
#define NHEADS  16
#define HEADDIM 64
#define CONVDIM 1280            // DINNER + 2*DSTATE
#define DINPROJ 2320            // 2*DINNER + 2*DSTATE + NHEADS
#define DINPROJP 2432           // padded to multiple of 128 for GEMM tiles
#define NLAYER  28
#define VOCABSZ 256
#define NROWS   (BATCH*SEQ)     // 12288
#define EPSV    1e-5f
#define NCH     8               // chunks per sequence
#define CH      96              // SEQ / NCH
#define STATESZ (HEADDIM*DSTATE) // 8192 floats per (b,h,chunk)

typedef __hip_bfloat16 bf16_t;
typedef __attribute__((ext_vector_type(8))) __bf16 bf16x8;
typedef __attribute__((ext_vector_type(4))) float floatx4;

__device__ __forceinline__ float siluf(float v) { return v / (1.f + expf(-v)); }

// ---------------- embedding gather ----------------
__global__ __launch_bounds__(256) void embed_kernel(const int* __restrict__ tok,
    const float* __restrict__ emb, float* __restrict__ hid) {
  int i = blockIdx.x * 256 + threadIdx.x;
  if (i >= NROWS * DMODEL) return;
  int r = i >> 9;               // / DMODEL
  int d = i & (DMODEL - 1);
  hid[i] = emb[(size_t)tok[r] * DMODEL + d];
}

// ---------------- weight conversions (per layer, tiny) ----------------
__global__ __launch_bounds__(256) void cvt_inproj_kernel(const float* __restrict__ src,
    bf16_t* __restrict__ dst) {
  int i = blockIdx.x * 256 + threadIdx.x;     // over DINPROJP*DMODEL
  int row = i >> 9, col = i & (DMODEL - 1);
  float v = (row < DINPROJ) ? src[(size_t)row * DMODEL + col] : 0.f;
  dst[i] = __float2bfloat16(v);
}

__global__ __launch_bounds__(256) void cvt_kernel(const float* __restrict__ src,
    bf16_t* __restrict__ dst, int n) {
  int i = blockIdx.x * 256 + threadIdx.x;
  if (i < n) dst[i] = __float2bfloat16(src[i]);
}

// ---------------- residual add + RMSNorm (512 cols), bf16 out ----------------
__global__ __launch_bounds__(128) void prenorm_kernel(const float* __restrict__ h,
    float* __restrict__ res, const float* __restrict__ w, bf16_t* __restrict__ xn) {
  int row = blockIdx.x;
  int tid = threadIdx.x;        // 128 threads, one float4 each (512 cols)
  const float4* h4 = (const float4*)(h + (size_t)row * DMODEL);
  float4* r4 = (float4*)(res + (size_t)row * DMODEL);
  float4 v = r4[tid];
  float4 a = h4[tid];
  v.x += a.x; v.y += a.y; v.z += a.z; v.w += a.w;
  r4[tid] = v;
  float ss = v.x * v.x + v.y * v.y + v.z * v.z + v.w * v.w;
  #pragma unroll
  for (int o = 32; o > 0; o >>= 1) ss += __shfl_down(ss, o);
  __shared__ float wred[2];
  if ((tid & 63) == 0) wred[tid >> 6] = ss;
  __syncthreads();
  float tot = wred[0] + wred[1];
  float scale = rsqrtf(tot / (float)DMODEL + EPSV);
  const float4* w4 = (const float4*)w;
  float4 wv = w4[tid];
  union { bf16_t b[4]; uint2 u; } pk;
  pk.b[0] = __float2bfloat16(v.x * scale * wv.x);
  pk.b[1] = __float2bfloat16(v.y * scale * wv.y);
  pk.b[2] = __float2bfloat16(v.z * scale * wv.z);
  pk.b[3] = __float2bfloat16(v.w * scale * wv.w);
  ((uint2*)(xn + (size_t)row * DMODEL))[tid] = pk.u;
}

// ---------------- bf16 MFMA GEMM: C[M,N] = A[M,K] * B[N,K]^T ----------------
// 128x128 tile, 4 waves, each wave 64x64 via 4x4 frags of 16x16x32 MFMA.
// B must be padded to a multiple of 128 rows (reads beyond N are staged but
// their products land in store-guarded columns).
__global__ __launch_bounds__(256) void gemm_bf16_bt(const bf16_t* __restrict__ A,
    const bf16_t* __restrict__ B, float* __restrict__ C, int M, int N, int K) {
  __shared__ bf16_t As[128 * 32];
  __shared__ bf16_t Bs[128 * 32];
  int tid = threadIdx.x;
  int m0 = blockIdx.y * 128;
  int n0 = blockIdx.x * 128;
  int w = tid >> 6, lane = tid & 63;
  int wm = (w >> 1) * 64, wn = (w & 1) * 64;
  int l16 = lane & 15, lq = lane >> 4;
  floatx4 acc[4][4];
  #pragma unroll
  for (int i = 0; i < 4; ++i)
    #pragma unroll
    for (int j = 0; j < 4; ++j)
      acc[i][j] = (floatx4){0.f, 0.f, 0.f, 0.f};
  int idx0 = tid, idx1 = tid + 256;
  int arow0 = idx0 >> 2, ak0 = (idx0 & 3) * 8;
  int arow1 = idx1 >> 2, ak1 = (idx1 & 3) * 8;
  const bf16_t* Abase = A + (size_t)m0 * K;
  const bf16_t* Bbase = B + (size_t)n0 * K;
  for (int k0 = 0; k0 < K; k0 += 32) {
    uint4 va0 = *(const uint4*)(Abase + (size_t)arow0 * K + k0 + ak0);
    uint4 va1 = *(const uint4*)(Abase + (size_t)arow1 * K + k0 + ak1);
    uint4 vb0 = *(const uint4*)(Bbase + (size_t)arow0 * K + k0 + ak0);
    uint4 vb1 = *(const uint4*)(Bbase + (size_t)arow1 * K + k0 + ak1);
    __syncthreads();
    *(uint4*)(As + idx0 * 8) = va0;
    *(uint4*)(As + idx1 * 8) = va1;
    *(uint4*)(Bs + idx0 * 8) = vb0;
    *(uint4*)(Bs + idx1 * 8) = vb1;
    __syncthreads();
    bf16x8 af[4], bfr[4];
    #pragma unroll
    for (int i = 0; i < 4; ++i)
      af[i] = *(const bf16x8*)(As + (wm + i * 16 + l16) * 32 + lq * 8);
    #pragma unroll
    for (int j = 0; j < 4; ++j)
      bfr[j] = *(const bf16x8*)(Bs + (wn + j * 16 + l16) * 32 + lq * 8);
    #pragma unroll
    for (int i = 0; i < 4; ++i)
      #pragma unroll
      for (int j = 0; j < 4; ++j)
        acc[i][j] = __builtin_amdgcn_mfma_f32_16x16x32_bf16(af[i], bfr[j], acc[i][j], 0, 0, 0);
  }
  // epilogue: C/D layout col=lane&15, row=(lane>>4)*4+reg  [m89/m91 verified]
  #pragma unroll
  for (int i = 0; i < 4; ++i) {
    #pragma unroll
    for (int j = 0; j < 4; ++j) {
      int n = n0 + wn + j * 16 + l16;
      if (n < N) {
        int mb = m0 + wm + i * 16 + lq * 4;
        #pragma unroll
        for (int r = 0; r < 4; ++r)
          C[(size_t)(mb + r) * N + n] = acc[i][j][r];
      }
    }
  }
}

// ---------------- dt = softplus(raw + bias); dA = exp(dt * A) ----------------
__global__ __launch_bounds__(256) void dt_kernel(const float* __restrict__ zx,
    const float* __restrict__ dt_bias, const float* __restrict__ A_log,
    float* __restrict__ dt, float* __restrict__ dA) {
  int i = blockIdx.x * 256 + threadIdx.x;
  if (i >= NROWS * NHEADS) return;
  int h = i & (NHEADS - 1);
  int row = i >> 4;
  float v = zx[(size_t)row * DINPROJ + (DINNER + CONVDIM) + h] + dt_bias[h];
  float sp = fmaxf(v, 0.f) + log1pf(expf(-fabsf(v)));
  float Ah = -expf(A_log[h]);
  dt[i] = sp;
  dA[i] = expf(sp * Ah);
}

// ---------------- causal conv (width 4) + silu ----------------
__global__ __launch_bounds__(256) void conv_kernel(const float* __restrict__ zx,
    const float* __restrict__ cw, const float* __restrict__ cb, float* __restrict__ out) {
  int c = blockIdx.x * 256 + threadIdx.x;      // 0..1279
  int bl = blockIdx.y;                         // 0..NROWS-1
  int t = bl % SEQ;
  float acc = cb[c];
  #pragma unroll
  for (int k = 0; k < 4; ++k) {
    int tt = t + k - 3;
    if (tt >= 0)
      acc += zx[(size_t)(bl + k - 3) * DINPROJ + DINNER + c] * cw[c * 4 + k];
  }
  out[(size_t)bl * CONVDIM + c] = siluf(acc);
}

// ---------------- chunked SSD scan, pass 1: local scan from zero state ----------------
__global__ __launch_bounds__(256) void scan_local_kernel(const float* __restrict__ conv,
    const float* __restrict__ dtb, const float* __restrict__ dAb,
    const float* __restrict__ Dp, float* __restrict__ y,
    float* __restrict__ state, float* __restrict__ chunkprod) {
  int c = blockIdx.x;
  int bh = blockIdx.y;
  int b = bh >> 4, h = bh & 15;
  int tid = threadIdx.x;
  int s = tid >> 6;               // wave id: n-slice [32s, 32s+32)
  int p = tid & 63;               // lane = headdim index
  float hs[32];
  #pragma unroll
  for (int j = 0; j < 32; ++j) hs[j] = 0.f;
  float Dh = Dp[h];
  float prod = 1.f;
  __shared__ float yred[8][4][64];
  const int nbase = DINNER + s * 32;
  const int tstart = c * CH;
  for (int t0 = 0; t0 < CH; t0 += 8) {
    #pragma unroll 1
    for (int tc = 0; tc < 8; ++tc) {
      int t = tstart + t0 + tc;
      size_t rbase = (size_t)(b * SEQ + t) * CONVDIM;
      float x = conv[rbase + h * HEADDIM + p];
      int dti = (b * SEQ + t) * NHEADS + h;
      float dtv = dtb[dti];
      float dAv = dAb[dti];
      float dtx = dtv * x;
      prod *= dAv;
      const float4* Bp = (const float4*)(conv + rbase + nbase);
      const float4* Cp = (const float4*)(conv + rbase + nbase + DSTATE);
      float y0 = 0.f, y1 = 0.f, y2 = 0.f, y3 = 0.f;
      #pragma unroll
      for (int q = 0; q < 8; ++q) {
        float4 Bv = Bp[q];
        float4 Cv = Cp[q];
        hs[q * 4 + 0] = dAv * hs[q * 4 + 0] + dtx * Bv.x; y0 += hs[q * 4 + 0] * Cv.x;
        hs[q * 4 + 1] = dAv * hs[q * 4 + 1] + dtx * Bv.y; y1 += hs[q * 4 + 1] * Cv.y;
        hs[q * 4 + 2] = dAv * hs[q * 4 + 2] + dtx * Bv.z; y2 += hs[q * 4 + 2] * Cv.z;
        hs[q * 4 + 3] = dAv * hs[q * 4 + 3] + dtx * Bv.w; y3 += hs[q * 4 + 3] * Cv.w;
      }
      float yp = (y0 + y1) + (y2 + y3);
      if (s == 0) yp += Dh * x;
      yred[tc][s][p] = yp;
    }
    __syncthreads();
    for (int i = tid; i < 512; i += 256) {
      int tc = i >> 6, pp = i & 63;
      float v = yred[tc][0][pp] + yred[tc][1][pp] + yred[tc][2][pp] + yred[tc][3][pp];
      y[((size_t)(b * SEQ + tstart + t0 + tc) * NHEADS + h) * HEADDIM + pp] = v;
    }
    __syncthreads();
  }
  size_t sbase = ((size_t)bh * NCH + c) * STATESZ;
  #pragma unroll
  for (int j = 0; j < 32; ++j)
    state[sbase + (size_t)(s * 32 + j) * HEADDIM + p] = hs[j];
  if (tid == 0) chunkprod[bh * NCH + c] = prod;
}

// ---------------- pass 2: sequential combine across chunks (in place) ----------------
__global__ __launch_bounds__(256) void state_combine_kernel(float* __restrict__ state,
    const float* __restrict__ chunkprod) {
  int bh = blockIdx.x;
  int tid = threadIdx.x;
  float hin[32];
  #pragma unroll
  for (int j = 0; j < 32; ++j) hin[j] = 0.f;
  size_t base = (size_t)bh * NCH * STATESZ + (size_t)tid * 32;
  for (int c = 0; c < NCH; ++c) {
    float4* sp = (float4*)(state + base + (size_t)c * STATESZ);
    float S[32];
    #pragma unroll
    for (int q = 0; q < 8; ++q) {
      float4 v = sp[q];
      S[q * 4 + 0] = v.x; S[q * 4 + 1] = v.y; S[q * 4 + 2] = v.z; S[q * 4 + 3] = v.w;
    }
    float P = chunkprod[bh * NCH + c];
    #pragma unroll
    for (int q = 0; q < 8; ++q)
      sp[q] = make_float4(hin[q * 4 + 0], hin[q * 4 + 1], hin[q * 4 + 2], hin[q * 4 + 3]);
    #pragma unroll
    for (int j = 0; j < 32; ++j) hin[j] = P * hin[j] + S[j];
  }
}

// ---------------- pass 3: y[t] += cumA_incl[t] * (C_t . H_in) ----------------
__global__ __launch_bounds__(256) void ycorr_kernel(const float* __restrict__ conv,
    const float* __restrict__ dAb, const float* __restrict__ state,
    float* __restrict__ y) {
  int c = blockIdx.x + 1;
  int bh = blockIdx.y;
  int b = bh >> 4, h = bh & 15;
  int tid = threadIdx.x;
  __shared__ float hlds[STATESZ];   // [n][p] layout
  __shared__ float cA[CH];
  const float4* sp = (const float4*)(state + ((size_t)bh * NCH + c) * STATESZ);
  float4* hl4 = (float4*)hlds;
  for (int i = tid; i < STATESZ / 4; i += 256) hl4[i] = sp[i];
  const int tstart = c * CH;
  if (tid < CH) cA[tid] = dAb[(b * SEQ + tstart + tid) * NHEADS + h];
  __syncthreads();
  for (int off = 1; off < CH; off <<= 1) {
    float tmp = 1.f;
    if (tid < CH && tid >= off) tmp = cA[tid - off];
    __syncthreads();
    if (tid < CH) cA[tid] *= tmp;
    __syncthreads();
  }
  int s = tid >> 6, p = tid & 63;
  for (int tt = s; tt < CH; tt += 4) {
    int t = tstart + tt;
    const float4* Cp = (const float4*)(conv + (size_t)(b * SEQ + t) * CONVDIM + DINNER + DSTATE);
    float acc = 0.f;
    #pragma unroll
    for (int nq = 0; nq < DSTATE / 4; ++nq) {
      float4 Cv = Cp[nq];
      acc += Cv.x * hlds[(nq * 4 + 0) * HEADDIM + p];
      acc += Cv.y * hlds[(nq * 4 + 1) * HEADDIM + p];
      acc += Cv.z * hlds[(nq * 4 + 2) * HEADDIM + p];
      acc += Cv.w * hlds[(nq * 4 + 3) * HEADDIM + p];
    }
    size_t yi = ((size_t)(b * SEQ + t) * NHEADS + h) * HEADDIM + p;
    y[yi] += cA[tt] * acc;
  }
}

// ---------------- gated RMSNorm over 1024, bf16 out ----------------
__global__ __launch_bounds__(256) void gated_norm_kernel(const float* __restrict__ y,
    const float* __restrict__ zx, const float* __restrict__ gw, bf16_t* __restrict__ out) {
  int row = blockIdx.x;
  int tid = threadIdx.x;
  const float4* y4 = (const float4*)(y + (size_t)row * DINNER);
  const float4* z4 = (const float4*)(zx + (size_t)row * DINPROJ);
  float4 yv = y4[tid];
  float4 zv = z4[tid];
  float4 g;
  g.x = yv.x * siluf(zv.x); g.y = yv.y * siluf(zv.y);
  g.z = yv.z * siluf(zv.z); g.w = yv.w * siluf(zv.w);
  float ss = g.x * g.x + g.y * g.y + g.z * g.z + g.w * g.w;
  #pragma unroll
  for (int o = 32; o > 0; o >>= 1) ss += __shfl_down(ss, o);
  __shared__ float red[4];
  if ((tid & 63) == 0) red[tid >> 6] = ss;
  __syncthreads();
  float tot = red[0] + red[1] + red[2] + red[3];
  float scale = rsqrtf(tot / (float)DINNER + EPSV);
  const float4* g4 = (const float4*)gw;
  float4 wv = g4[tid];
  union { bf16_t b[4]; uint2 u; } pk;
  pk.b[0] = __float2bfloat16(g.x * scale * wv.x);
  pk.b[1] = __float2bfloat16(g.y * scale * wv.y);
  pk.b[2] = __float2bfloat16(g.z * scale * wv.z);
  pk.b[3] = __float2bfloat16(g.w * scale * wv.w);
  ((uint2*)(out + (size_t)row * DINNER))[tid] = pk.u;
}

// ---------------- per-row loss: lse - logit[target] ----------------
__global__ __launch_bounds__(256) void rowloss_kernel(const float* __restrict__ logits,
    const int* __restrict__ targets, float* __restrict__ rl) {
  int row = blockIdx.x * 4 + (threadIdx.x >> 6);
  int lane = threadIdx.x & 63;
  const float* lr = logits + (size_t)row * VOCABSZ;
  float4 v = ((const float4*)lr)[lane];
  float mx = fmaxf(fmaxf(v.x, v.y), fmaxf(v.z, v.w));
  #pragma unroll
  for (int o = 32; o > 0; o >>= 1) mx = fmaxf(mx, __shfl_down(mx, o));
  mx = __shfl(mx, 0);
  float e = expf(v.x - mx) + expf(v.y - mx) + expf(v.z - mx) + expf(v.w - mx);
  #pragma unroll
  for (int o = 32; o > 0; o >>= 1) e += __shfl_down(e, o);
  if (lane == 0) {
    float lse = logf(e) + mx;
    rl[row] = lse - lr[targets[row]];
  }
}

__global__ __launch_bounds__(256) void loss_reduce_kernel(const float* __restrict__ rl,
    float* __restrict__ out) {
  int tid = threadIdx.x;
  float ssum = 0.f;
  for (int i = tid; i < NROWS; i += 256) ssum += rl[i];
  #pragma unroll
  for (int o = 32; o > 0; o >>= 1) ssum += __shfl_down(ssum, o);
  __shared__ float red[4];
  if ((tid & 63) == 0) red[tid >> 6] = ssum;
  __syncthreads();
  if (tid == 0) out[0] = (red[0] + red[1] + red[2] + red[3]) / (float)NROWS;
}

extern "C" void kernel_launch(void* const* d_in, const int* in_sizes, int n_in,
                              void* d_out, int out_size, void* d_ws, size_t ws_size,
                              hipStream_t stream) {
  const int*   tokens       = (const int*)d_in[0];
  const int*   targets      = (const int*)d_in[1];
  const float* embedding    = (const float*)d_in[2];
  const float* in_proj_w    = (const float*)d_in[3];
  const float* conv_w       = (const float*)d_in[4];
  const float* conv_b       = (const float*)d_in[5];
  const float* dt_bias      = (const float*)d_in[6];
  const float* A_log        = (const float*)d_in[7];
  const float* Dp           = (const float*)d_in[8];
  const float* gnorm_w      = (const float*)d_in[9];
  const float* out_proj_w   = (const float*)d_in[10];
  const float* block_norm_w = (const float*)d_in[11];
  const float* norm_f_w     = (const float*)d_in[12];
  float* out = (float*)d_out;

  float* ws = (float*)d_ws;
  size_t off = 0;
  float* hidden   = ws + off; off += (size_t)NROWS * DMODEL;
  float* residual = ws + off; off += (size_t)NROWS * DMODEL;
  float* zx       = ws + off; off += (size_t)NROWS * DINPROJ;
  float* convo    = ws + off; off += (size_t)NROWS * CONVDIM;
  float* dtb      = ws + off; off += (size_t)NROWS * NHEADS;
  float* dAb      = ws + off; off += (size_t)NROWS * NHEADS;
  float* ybuf     = ws + off; off += (size_t)NROWS * DINNER;
  float* cprod    = ws + off; off += (size_t)BATCH * NHEADS * NCH;
  float* rowloss  = ws + off; off += NROWS;
  bf16_t* w_in_bf  = (bf16_t*)(ws + off); off += (size_t)DINPROJP * DMODEL / 2;
  bf16_t* w_out_bf = (bf16_t*)(ws + off); off += (size_t)DMODEL * DINNER / 2;
  bf16_t* w_emb_bf = (bf16_t*)(ws + off); off += (size_t)VOCABSZ * DMODEL / 2;
  // union region: state (16.78M floats) vs bf16 activations (disjoint live ranges)
  float*  state  = ws + off;
  bf16_t* xn_bf  = (bf16_t*)(ws + off);   // live prenorm -> gemm1
  bf16_t* yn_bf  = (bf16_t*)(ws + off);   // live gated_norm -> gemm2
  off += (size_t)BATCH * NHEADS * NCH * STATESZ;

  hipMemsetAsync(residual, 0, (size_t)NROWS * DMODEL * sizeof(float), stream);
  embed_kernel<<<NROWS * DMODEL / 256, 256, 0, stream>>>(tokens, embedding, hidden);
  cvt_kernel<<<(VOCABSZ * DMODEL) / 256, 256, 0, stream>>>(embedding, w_emb_bf, VOCABSZ * DMODEL);

  for (int l = 0; l < NLAYER; ++l) {
    const float* ipw = in_proj_w + (size_t)l * DINPROJ * DMODEL;
    const float* cw  = conv_w + (size_t)l * CONVDIM * 4;
    const float* cb  = conv_b + (size_t)l * CONVDIM;
    const float* dtbias_l = dt_bias + (size_t)l * NHEADS;
    const float* alog_l   = A_log + (size_t)l * NHEADS;
    const float* D_l      = Dp + (size_t)l * NHEADS;
    const float* gw  = gnorm_w + (size_t)l * DINNER;
    const float* opw = out_proj_w + (size_t)l * DMODEL * DINNER;
    const float* bnw = block_norm_w + (size_t)l * DMODEL;

    cvt_inproj_kernel<<<(DINPROJP * DMODEL) / 256, 256, 0, stream>>>(ipw, w_in_bf);
    cvt_kernel<<<(DMODEL * DINNER) / 256, 256, 0, stream>>>(opw, w_out_bf, DMODEL * DINNER);
    prenorm_kernel<<<NROWS, 128, 0, stream>>>(hidden, residual, bnw, xn_bf);
    dim3 g1(DINPROJP / 128, NROWS / 128);
    gemm_bf16_bt<<<g1, 256, 0, stream>>>(xn_bf, w_in_bf, zx, NROWS, DINPROJ, DMODEL);
    dt_kernel<<<(NROWS * NHEADS) / 256, 256, 0, stream>>>(zx, dtbias_l, alog_l, dtb, dAb);
    conv_kernel<<<dim3(CONVDIM / 256, NROWS), 256, 0, stream>>>(zx, cw, cb, convo);
    scan_local_kernel<<<dim3(NCH, BATCH * NHEADS), 256, 0, stream>>>(
        convo, dtb, dAb, D_l, ybuf, state, cprod);
    state_combine_kernel<<<BATCH * NHEADS, 256, 0, stream>>>(state, cprod);
    ycorr_kernel<<<dim3(NCH - 1, BATCH * NHEADS), 256, 0, stream>>>(
        convo, dAb, state, ybuf);
    gated_norm_kernel<<<NROWS, 256, 0, stream>>>(ybuf, zx, gw, yn_bf);
    dim3 g2(DMODEL / 128, NROWS / 128);
    gemm_bf16_bt<<<g2, 256, 0, stream>>>(yn_bf, w_out_bf, hidden, NROWS, DMODEL, DINNER);
  }

  prenorm_kernel<<<NROWS, 128, 0, stream>>>(hidden, residual, norm_f_w, xn_bf);
  dim3 g3(VOCABSZ / 128, NROWS / 128);
  gemm_bf16_bt<<<g3, 256, 0, stream>>>(xn_bf, w_emb_bf, out, NROWS, VOCABSZ, DMODEL);
  rowloss_kernel<<<NROWS / 4, 256, 0, stream>>>(out, targets, rowloss);
  loss_reduce_kernel<<<1, 256, 0, stream>>>(rowloss, out + (size_t)(out_size - 1));
}

// Round 4
// 26983.939 us; speedup vs baseline: 1.6696x; 1.1352x over previous
//
#include <hip/hip_runtime.h>
#include <hip/hip_bf16.h>
#include <math.h>

#define BATCH   16
#define SEQ     768
#define DMODEL  512
#define DSTATE  128
#define DINNER  1024
#define NHEADS  16
#define HEADDIM 64
#define CONVDIM 1280            // DINNER + 2*DSTATE
#define DINPROJ 2320            // 2*DINNER + 2*DSTATE + NHEADS
#define DINPROJP 2432           // padded to multiple of 128 for GEMM tiles
#define NLAYER  28
#define VOCABSZ 256
#define NROWS   (BATCH*SEQ)     // 12288
#define EPSV    1e-5f
#define NCH     8               // chunks per sequence
#define CH      96              // SEQ / NCH
#define STATESZ (HEADDIM*DSTATE) // 8192 floats per (b,h,chunk)

typedef __hip_bfloat16 bf16_t;
typedef __attribute__((ext_vector_type(8))) __bf16 bf16x8;
typedef __attribute__((ext_vector_type(4))) float floatx4;

__device__ __forceinline__ float siluf(float v) { return v / (1.f + expf(-v)); }

// ---------------- embedding gather ----------------
__global__ __launch_bounds__(256) void embed_kernel(const int* __restrict__ tok,
    const float* __restrict__ emb, float* __restrict__ hid) {
  int i = blockIdx.x * 256 + threadIdx.x;
  if (i >= NROWS * DMODEL) return;
  int r = i >> 9;               // / DMODEL
  int d = i & (DMODEL - 1);
  hid[i] = emb[(size_t)tok[r] * DMODEL + d];
}

// ---------------- per-layer weight conversion, one dispatch ----------------
__global__ __launch_bounds__(256) void cvt_weights_kernel(const float* __restrict__ ipw,
    const float* __restrict__ opw, bf16_t* __restrict__ win, bf16_t* __restrict__ wout) {
  int i = blockIdx.x * 256 + threadIdx.x;
  const int n1 = DINPROJP * DMODEL;
  if (i < n1) {
    int row = i >> 9, col = i & (DMODEL - 1);
    float v = (row < DINPROJ) ? ipw[(size_t)row * DMODEL + col] : 0.f;
    win[i] = __float2bfloat16(v);
  } else {
    int j = i - n1;
    if (j < DMODEL * DINNER) wout[j] = __float2bfloat16(opw[j]);
  }
}

__global__ __launch_bounds__(256) void cvt_kernel(const float* __restrict__ src,
    bf16_t* __restrict__ dst, int n) {
  int i = blockIdx.x * 256 + threadIdx.x;
  if (i < n) dst[i] = __float2bfloat16(src[i]);
}

// ---------------- residual add + RMSNorm (512 cols), bf16 out ----------------
__global__ __launch_bounds__(128) void prenorm_kernel(const float* __restrict__ h,
    float* __restrict__ res, const float* __restrict__ w, bf16_t* __restrict__ xn) {
  int row = blockIdx.x;
  int tid = threadIdx.x;        // 128 threads, one float4 each (512 cols)
  const float4* h4 = (const float4*)(h + (size_t)row * DMODEL);
  float4* r4 = (float4*)(res + (size_t)row * DMODEL);
  float4 v = r4[tid];
  float4 a = h4[tid];
  v.x += a.x; v.y += a.y; v.z += a.z; v.w += a.w;
  r4[tid] = v;
  float ss = v.x * v.x + v.y * v.y + v.z * v.z + v.w * v.w;
  #pragma unroll
  for (int o = 32; o > 0; o >>= 1) ss += __shfl_down(ss, o);
  __shared__ float wred[2];
  if ((tid & 63) == 0) wred[tid >> 6] = ss;
  __syncthreads();
  float tot = wred[0] + wred[1];
  float scale = rsqrtf(tot / (float)DMODEL + EPSV);
  const float4* w4 = (const float4*)w;
  float4 wv = w4[tid];
  union { bf16_t b[4]; uint2 u; } pk;
  pk.b[0] = __float2bfloat16(v.x * scale * wv.x);
  pk.b[1] = __float2bfloat16(v.y * scale * wv.y);
  pk.b[2] = __float2bfloat16(v.z * scale * wv.z);
  pk.b[3] = __float2bfloat16(v.w * scale * wv.w);
  ((uint2*)(xn + (size_t)row * DMODEL))[tid] = pk.u;
}

// ---------------- bf16 MFMA GEMM: C[M,N] = A[M,K] * B[N,K]^T ----------------
__global__ __launch_bounds__(256) void gemm_bf16_bt(const bf16_t* __restrict__ A,
    const bf16_t* __restrict__ B, float* __restrict__ C, int M, int N, int K) {
  __shared__ bf16_t As[128 * 32];
  __shared__ bf16_t Bs[128 * 32];
  int tid = threadIdx.x;
  int m0 = blockIdx.y * 128;
  int n0 = blockIdx.x * 128;
  int w = tid >> 6, lane = tid & 63;
  int wm = (w >> 1) * 64, wn = (w & 1) * 64;
  int l16 = lane & 15, lq = lane >> 4;
  floatx4 acc[4][4];
  #pragma unroll
  for (int i = 0; i < 4; ++i)
    #pragma unroll
    for (int j = 0; j < 4; ++j)
      acc[i][j] = (floatx4){0.f, 0.f, 0.f, 0.f};
  int idx0 = tid, idx1 = tid + 256;
  int arow0 = idx0 >> 2, ak0 = (idx0 & 3) * 8;
  int arow1 = idx1 >> 2, ak1 = (idx1 & 3) * 8;
  const bf16_t* Abase = A + (size_t)m0 * K;
  const bf16_t* Bbase = B + (size_t)n0 * K;
  for (int k0 = 0; k0 < K; k0 += 32) {
    uint4 va0 = *(const uint4*)(Abase + (size_t)arow0 * K + k0 + ak0);
    uint4 va1 = *(const uint4*)(Abase + (size_t)arow1 * K + k0 + ak1);
    uint4 vb0 = *(const uint4*)(Bbase + (size_t)arow0 * K + k0 + ak0);
    uint4 vb1 = *(const uint4*)(Bbase + (size_t)arow1 * K + k0 + ak1);
    __syncthreads();
    *(uint4*)(As + idx0 * 8) = va0;
    *(uint4*)(As + idx1 * 8) = va1;
    *(uint4*)(Bs + idx0 * 8) = vb0;
    *(uint4*)(Bs + idx1 * 8) = vb1;
    __syncthreads();
    bf16x8 af[4], bfr[4];
    #pragma unroll
    for (int i = 0; i < 4; ++i)
      af[i] = *(const bf16x8*)(As + (wm + i * 16 + l16) * 32 + lq * 8);
    #pragma unroll
    for (int j = 0; j < 4; ++j)
      bfr[j] = *(const bf16x8*)(Bs + (wn + j * 16 + l16) * 32 + lq * 8);
    #pragma unroll
    for (int i = 0; i < 4; ++i)
      #pragma unroll
      for (int j = 0; j < 4; ++j)
        acc[i][j] = __builtin_amdgcn_mfma_f32_16x16x32_bf16(af[i], bfr[j], acc[i][j], 0, 0, 0);
  }
  #pragma unroll
  for (int i = 0; i < 4; ++i) {
    #pragma unroll
    for (int j = 0; j < 4; ++j) {
      int n = n0 + wn + j * 16 + l16;
      if (n < N) {
        int mb = m0 + wm + i * 16 + lq * 4;
        #pragma unroll
        for (int r = 0; r < 4; ++r)
          C[(size_t)(mb + r) * N + n] = acc[i][j][r];
      }
    }
  }
}

// ---------------- fused causal conv (width 4) + silu + dt/dA ----------------
// one block per row, 320 threads: each thread one float4 of CONVDIM
__global__ __launch_bounds__(320) void convdt_kernel(const float* __restrict__ zx,
    const float* __restrict__ cw, const float* __restrict__ cb,
    const float* __restrict__ dt_bias, const float* __restrict__ A_log,
    float* __restrict__ out, float* __restrict__ dt, float* __restrict__ dA) {
  int bl = blockIdx.x;                         // 0..NROWS-1
  int t = bl % SEQ;
  int tid = threadIdx.x;                       // 0..319
  int c = tid * 4;
  const float* base = zx + (size_t)bl * DINPROJ + DINNER + c;
  float4 acc = *(const float4*)(cb + c);
  #pragma unroll
  for (int k = 0; k < 4; ++k) {
    int tt = t + k - 3;
    if (tt >= 0) {
      float4 v = *(const float4*)(base + (ptrdiff_t)(k - 3) * DINPROJ);
      acc.x += v.x * cw[(c + 0) * 4 + k];
      acc.y += v.y * cw[(c + 1) * 4 + k];
      acc.z += v.z * cw[(c + 2) * 4 + k];
      acc.w += v.w * cw[(c + 3) * 4 + k];
    }
  }
  float4 o;
  o.x = siluf(acc.x); o.y = siluf(acc.y); o.z = siluf(acc.z); o.w = siluf(acc.w);
  *(float4*)(out + (size_t)bl * CONVDIM + c) = o;
  if (tid < NHEADS) {
    int h = tid;
    float v = zx[(size_t)bl * DINPROJ + (DINNER + CONVDIM) + h] + dt_bias[h];
    float sp = fmaxf(v, 0.f) + log1pf(expf(-fabsf(v)));
    float Ah = -expf(A_log[h]);
    dt[bl * NHEADS + h] = sp;
    dA[bl * NHEADS + h] = expf(sp * Ah);
  }
}

// ---------------- chunked SSD scan, pass 1: local scan from zero state ----------------
__global__ __launch_bounds__(256) void scan_local_kernel(const float* __restrict__ conv,
    const float* __restrict__ dtb, const float* __restrict__ dAb,
    const float* __restrict__ Dp, float* __restrict__ y,
    float* __restrict__ state, float* __restrict__ chunkprod) {
  int c = blockIdx.x;
  int bh = blockIdx.y;
  int b = bh >> 4, h = bh & 15;
  int tid = threadIdx.x;
  int s = tid >> 6;               // wave id: n-slice [32s, 32s+32)
  int p = tid & 63;               // lane = headdim index
  float hs[32];
  #pragma unroll
  for (int j = 0; j < 32; ++j) hs[j] = 0.f;
  float Dh = Dp[h];
  float prod = 1.f;
  __shared__ float yred[8][4][64];
  const int nbase = DINNER + s * 32;
  const int tstart = c * CH;
  for (int t0 = 0; t0 < CH; t0 += 8) {
    #pragma unroll 1
    for (int tc = 0; tc < 8; ++tc) {
      int t = tstart + t0 + tc;
      size_t rbase = (size_t)(b * SEQ + t) * CONVDIM;
      float x = conv[rbase + h * HEADDIM + p];
      int dti = (b * SEQ + t) * NHEADS + h;
      float dtv = dtb[dti];
      float dAv = dAb[dti];
      float dtx = dtv * x;
      prod *= dAv;
      const float4* Bp = (const float4*)(conv + rbase + nbase);
      const float4* Cp = (const float4*)(conv + rbase + nbase + DSTATE);
      float y0 = 0.f, y1 = 0.f, y2 = 0.f, y3 = 0.f;
      #pragma unroll
      for (int q = 0; q < 8; ++q) {
        float4 Bv = Bp[q];
        float4 Cv = Cp[q];
        hs[q * 4 + 0] = dAv * hs[q * 4 + 0] + dtx * Bv.x; y0 += hs[q * 4 + 0] * Cv.x;
        hs[q * 4 + 1] = dAv * hs[q * 4 + 1] + dtx * Bv.y; y1 += hs[q * 4 + 1] * Cv.y;
        hs[q * 4 + 2] = dAv * hs[q * 4 + 2] + dtx * Bv.z; y2 += hs[q * 4 + 2] * Cv.z;
        hs[q * 4 + 3] = dAv * hs[q * 4 + 3] + dtx * Bv.w; y3 += hs[q * 4 + 3] * Cv.w;
      }
      float yp = (y0 + y1) + (y2 + y3);
      if (s == 0) yp += Dh * x;
      yred[tc][s][p] = yp;
    }
    __syncthreads();
    for (int i = tid; i < 512; i += 256) {
      int tc = i >> 6, pp = i & 63;
      float v = yred[tc][0][pp] + yred[tc][1][pp] + yred[tc][2][pp] + yred[tc][3][pp];
      y[((size_t)(b * SEQ + tstart + t0 + tc) * NHEADS + h) * HEADDIM + pp] = v;
    }
    __syncthreads();
  }
  size_t sbase = ((size_t)bh * NCH + c) * STATESZ;
  #pragma unroll
  for (int j = 0; j < 32; ++j)
    state[sbase + (size_t)(s * 32 + j) * HEADDIM + p] = hs[j];
  if (tid == 0) chunkprod[bh * NCH + c] = prod;
}

// ---------------- pass 2: sequential combine across chunks (coalesced) ----------------
// grid 2048 = 256 bh x 8 parts; each thread owns one float4 of the state slab
__global__ __launch_bounds__(256) void state_combine_kernel(float* __restrict__ state,
    const float* __restrict__ chunkprod) {
  int bh = blockIdx.x >> 3;
  int part = blockIdx.x & 7;
  int idx = part * 256 + threadIdx.x;      // float4 index 0..2047
  float4 hin = make_float4(0.f, 0.f, 0.f, 0.f);
  size_t base = (size_t)bh * NCH * STATESZ + (size_t)idx * 4;
  for (int c = 0; c < NCH; ++c) {
    float4* sp = (float4*)(state + base + (size_t)c * STATESZ);
    float4 S = *sp;
    *sp = hin;
    float P = chunkprod[bh * NCH + c];
    hin.x = P * hin.x + S.x; hin.y = P * hin.y + S.y;
    hin.z = P * hin.z + S.z; hin.w = P * hin.w + S.w;
  }
}

// ---------------- pass 3: y[t] += cumA_incl[t] * (C_t . H_in) ----------------
// loop-swapped: n-quad outer, acc[CH/4] in registers, H read once per n-quad
__global__ __launch_bounds__(256) void ycorr_kernel(const float* __restrict__ conv,
    const float* __restrict__ dAb, const float* __restrict__ state,
    float* __restrict__ y) {
  int c = blockIdx.x + 1;
  int bh = blockIdx.y;
  int b = bh >> 4, h = bh & 15;
  int tid = threadIdx.x;
  __shared__ float hlds[STATESZ];   // [n][p] layout, bank=p%32 -> 2-way (free)
  __shared__ float cA[CH];
  const float4* sp = (const float4*)(state + ((size_t)bh * NCH + c) * STATESZ);
  float4* hl4 = (float4*)hlds;
  for (int i = tid; i < STATESZ / 4; i += 256) hl4[i] = sp[i];
  const int tstart = c * CH;
  if (tid < CH) cA[tid] = dAb[(b * SEQ + tstart + tid) * NHEADS + h];
  __syncthreads();
  for (int off = 1; off < CH; off <<= 1) {
    float tmp = 1.f;
    if (tid < CH && tid >= off) tmp = cA[tid - off];
    __syncthreads();
    if (tid < CH) cA[tid] *= tmp;
    __syncthreads();
  }
  int s = tid >> 6, p = tid & 63;
  float acc[CH / 4];
  #pragma unroll
  for (int i = 0; i < CH / 4; ++i) acc[i] = 0.f;
  const float* Cbase = conv + (size_t)(b * SEQ + tstart) * CONVDIM + DINNER + DSTATE;
  for (int nq = 0; nq < DSTATE / 4; ++nq) {
    float h0 = hlds[(nq * 4 + 0) * HEADDIM + p];
    float h1 = hlds[(nq * 4 + 1) * HEADDIM + p];
    float h2 = hlds[(nq * 4 + 2) * HEADDIM + p];
    float h3 = hlds[(nq * 4 + 3) * HEADDIM + p];
    #pragma unroll
    for (int i = 0; i < CH / 4; ++i) {
      int tt = s + i * 4;
      float4 Cv = *(const float4*)(Cbase + (size_t)tt * CONVDIM + nq * 4);
      acc[i] += Cv.x * h0 + Cv.y * h1 + Cv.z * h2 + Cv.w * h3;
    }
  }
  #pragma unroll
  for (int i = 0; i < CH / 4; ++i) {
    int tt = s + i * 4;
    size_t yi = ((size_t)(b * SEQ + tstart + tt) * NHEADS + h) * HEADDIM + p;
    y[yi] += cA[tt] * acc[i];
  }
}

// ---------------- gated RMSNorm over 1024, bf16 out ----------------
__global__ __launch_bounds__(256) void gated_norm_kernel(const float* __restrict__ y,
    const float* __restrict__ zx, const float* __restrict__ gw, bf16_t* __restrict__ out) {
  int row = blockIdx.x;
  int tid = threadIdx.x;
  const float4* y4 = (const float4*)(y + (size_t)row * DINNER);
  const float4* z4 = (const float4*)(zx + (size_t)row * DINPROJ);
  float4 yv = y4[tid];
  float4 zv = z4[tid];
  float4 g;
  g.x = yv.x * siluf(zv.x); g.y = yv.y * siluf(zv.y);
  g.z = yv.z * siluf(zv.z); g.w = yv.w * siluf(zv.w);
  float ss = g.x * g.x + g.y * g.y + g.z * g.z + g.w * g.w;
  #pragma unroll
  for (int o = 32; o > 0; o >>= 1) ss += __shfl_down(ss, o);
  __shared__ float red[4];
  if ((tid & 63) == 0) red[tid >> 6] = ss;
  __syncthreads();
  float tot = red[0] + red[1] + red[2] + red[3];
  float scale = rsqrtf(tot / (float)DINNER + EPSV);
  const float4* g4 = (const float4*)gw;
  float4 wv = g4[tid];
  union { bf16_t b[4]; uint2 u; } pk;
  pk.b[0] = __float2bfloat16(g.x * scale * wv.x);
  pk.b[1] = __float2bfloat16(g.y * scale * wv.y);
  pk.b[2] = __float2bfloat16(g.z * scale * wv.z);
  pk.b[3] = __float2bfloat16(g.w * scale * wv.w);
  ((uint2*)(out + (size_t)row * DINNER))[tid] = pk.u;
}

// ---------------- per-row loss: lse - logit[target] ----------------
__global__ __launch_bounds__(256) void rowloss_kernel(const float* __restrict__ logits,
    const int* __restrict__ targets, float* __restrict__ rl) {
  int row = blockIdx.x * 4 + (threadIdx.x >> 6);
  int lane = threadIdx.x & 63;
  const float* lr = logits + (size_t)row * VOCABSZ;
  float4 v = ((const float4*)lr)[lane];
  float mx = fmaxf(fmaxf(v.x, v.y), fmaxf(v.z, v.w));
  #pragma unroll
  for (int o = 32; o > 0; o >>= 1) mx = fmaxf(mx, __shfl_down(mx, o));
  mx = __shfl(mx, 0);
  float e = expf(v.x - mx) + expf(v.y - mx) + expf(v.z - mx) + expf(v.w - mx);
  #pragma unroll
  for (int o = 32; o > 0; o >>= 1) e += __shfl_down(e, o);
  if (lane == 0) {
    float lse = logf(e) + mx;
    rl[row] = lse - lr[targets[row]];
  }
}

__global__ __launch_bounds__(256) void loss_reduce_kernel(const float* __restrict__ rl,
    float* __restrict__ out) {
  int tid = threadIdx.x;
  float ssum = 0.f;
  for (int i = tid; i < NROWS; i += 256) ssum += rl[i];
  #pragma unroll
  for (int o = 32; o > 0; o >>= 1) ssum += __shfl_down(ssum, o);
  __shared__ float red[4];
  if ((tid & 63) == 0) red[tid >> 6] = ssum;
  __syncthreads();
  if (tid == 0) out[0] = (red[0] + red[1] + red[2] + red[3]) / (float)NROWS;
}

extern "C" void kernel_launch(void* const* d_in, const int* in_sizes, int n_in,
                              void* d_out, int out_size, void* d_ws, size_t ws_size,
                              hipStream_t stream) {
  const int*   tokens       = (const int*)d_in[0];
  const int*   targets      = (const int*)d_in[1];
  const float* embedding    = (const float*)d_in[2];
  const float* in_proj_w    = (const float*)d_in[3];
  const float* conv_w       = (const float*)d_in[4];
  const float* conv_b       = (const float*)d_in[5];
  const float* dt_bias      = (const float*)d_in[6];
  const float* A_log        = (const float*)d_in[7];
  const float* Dp           = (const float*)d_in[8];
  const float* gnorm_w      = (const float*)d_in[9];
  const float* out_proj_w   = (const float*)d_in[10];
  const float* block_norm_w = (const float*)d_in[11];
  const float* norm_f_w     = (const float*)d_in[12];
  float* out = (float*)d_out;

  float* ws = (float*)d_ws;
  size_t off = 0;
  float* hidden   = ws + off; off += (size_t)NROWS * DMODEL;
  float* residual = ws + off; off += (size_t)NROWS * DMODEL;
  float* zx       = ws + off; off += (size_t)NROWS * DINPROJ;
  float* convo    = ws + off; off += (size_t)NROWS * CONVDIM;
  float* dtb      = ws + off; off += (size_t)NROWS * NHEADS;
  float* dAb      = ws + off; off += (size_t)NROWS * NHEADS;
  float* ybuf     = ws + off; off += (size_t)NROWS * DINNER;
  float* cprod    = ws + off; off += (size_t)BATCH * NHEADS * NCH;
  float* rowloss  = ws + off; off += NROWS;
  bf16_t* w_in_bf  = (bf16_t*)(ws + off); off += (size_t)DINPROJP * DMODEL / 2;
  bf16_t* w_out_bf = (bf16_t*)(ws + off); off += (size_t)DMODEL * DINNER / 2;
  bf16_t* w_emb_bf = (bf16_t*)(ws + off); off += (size_t)VOCABSZ * DMODEL / 2;
  // union region: state (16.78M floats) vs bf16 activations (disjoint live ranges)
  float*  state  = ws + off;
  bf16_t* xn_bf  = (bf16_t*)(ws + off);   // live prenorm -> gemm1
  bf16_t* yn_bf  = (bf16_t*)(ws + off);   // live gated_norm -> gemm2
  off += (size_t)BATCH * NHEADS * NCH * STATESZ;

  hipMemsetAsync(residual, 0, (size_t)NROWS * DMODEL * sizeof(float), stream);
  embed_kernel<<<NROWS * DMODEL / 256, 256, 0, stream>>>(tokens, embedding, hidden);
  cvt_kernel<<<(VOCABSZ * DMODEL) / 256, 256, 0, stream>>>(embedding, w_emb_bf, VOCABSZ * DMODEL);

  const int cvt_total = DINPROJP * DMODEL + DMODEL * DINNER;
  for (int l = 0; l < NLAYER; ++l) {
    const float* ipw = in_proj_w + (size_t)l * DINPROJ * DMODEL;
    const float* cw  = conv_w + (size_t)l * CONVDIM * 4;
    const float* cb  = conv_b + (size_t)l * CONVDIM;
    const float* dtbias_l = dt_bias + (size_t)l * NHEADS;
    const float* alog_l   = A_log + (size_t)l * NHEADS;
    const float* D_l      = Dp + (size_t)l * NHEADS;
    const float* gw  = gnorm_w + (size_t)l * DINNER;
    const float* opw = out_proj_w + (size_t)l * DMODEL * DINNER;
    const float* bnw = block_norm_w + (size_t)l * DMODEL;

    cvt_weights_kernel<<<(cvt_total + 255) / 256, 256, 0, stream>>>(ipw, opw, w_in_bf, w_out_bf);
    prenorm_kernel<<<NROWS, 128, 0, stream>>>(hidden, residual, bnw, xn_bf);
    dim3 g1(DINPROJP / 128, NROWS / 128);
    gemm_bf16_bt<<<g1, 256, 0, stream>>>(xn_bf, w_in_bf, zx, NROWS, DINPROJ, DMODEL);
    convdt_kernel<<<NROWS, 320, 0, stream>>>(zx, cw, cb, dtbias_l, alog_l, convo, dtb, dAb);
    scan_local_kernel<<<dim3(NCH, BATCH * NHEADS), 256, 0, stream>>>(
        convo, dtb, dAb, D_l, ybuf, state, cprod);
    state_combine_kernel<<<BATCH * NHEADS * 8, 256, 0, stream>>>(state, cprod);
    ycorr_kernel<<<dim3(NCH - 1, BATCH * NHEADS), 256, 0, stream>>>(
        convo, dAb, state, ybuf);
    gated_norm_kernel<<<NROWS, 256, 0, stream>>>(ybuf, zx, gw, yn_bf);
    dim3 g2(DMODEL / 128, NROWS / 128);
    gemm_bf16_bt<<<g2, 256, 0, stream>>>(yn_bf, w_out_bf, hidden, NROWS, DMODEL, DINNER);
  }

  prenorm_kernel<<<NROWS, 128, 0, stream>>>(hidden, residual, norm_f_w, xn_bf);
  dim3 g3(VOCABSZ / 128, NROWS / 128);
  gemm_bf16_bt<<<g3, 256, 0, stream>>>(xn_bf, w_emb_bf, out, NROWS, VOCABSZ, DMODEL);
  rowloss_kernel<<<NROWS / 4, 256, 0, stream>>>(out, targets, rowloss);
  loss_reduce_kernel<<<1, 256, 0, stream>>>(rowloss, out + (size_t)(out_size - 1));
}

// Round 5
// 25891.013 us; speedup vs baseline: 1.7401x; 1.0422x over previous
//
#include <hip/hip_runtime.h>
#include <hip/hip_bf16.h>
#include <math.h>

#define BATCH   16
#define SEQ     768
#define DMODEL  512
#define DSTATE  128
#define DINNER  1024
#define NHEADS  16
#define HEADDIM 64
#define CONVDIM 1280            // DINNER + 2*DSTATE
#define DINPROJ 2320            // 2*DINNER + 2*DSTATE + NHEADS
#define DINPROJP 2432           // padded to multiple of 128 for GEMM tiles
#define NLAYER  28
#define VOCABSZ 256
#define NROWS   (BATCH*SEQ)     // 12288
#define EPSV    1e-5f
#define NCH     8               // chunks per sequence
#define CH      96              // SEQ / NCH
#define STATESZ (HEADDIM*DSTATE) // 8192 floats per (b,h,chunk)

typedef __hip_bfloat16 bf16_t;
typedef __attribute__((ext_vector_type(8))) __bf16 bf16x8;
typedef __attribute__((ext_vector_type(4))) float floatx4;

__device__ __forceinline__ float siluf(float v) { return v / (1.f + expf(-v)); }

// ---------------- embed + residual zero + embedding bf16 cvt, one dispatch ----------------
__global__ __launch_bounds__(256) void embed_kernel(const int* __restrict__ tok,
    const float* __restrict__ emb, float* __restrict__ hid, float* __restrict__ res,
    bf16_t* __restrict__ w_emb_bf) {
  int i = blockIdx.x * 256 + threadIdx.x;
  const int total = NROWS * DMODEL;
  if (i < total) {
    int r = i >> 9;               // / DMODEL
    int d = i & (DMODEL - 1);
    hid[i] = emb[(size_t)tok[r] * DMODEL + d];
    res[i] = 0.f;
  } else {
    int j = i - total;
    if (j < VOCABSZ * DMODEL) w_emb_bf[j] = __float2bfloat16(emb[j]);
  }
}

// ---------------- per-layer weight conversion, one dispatch ----------------
__global__ __launch_bounds__(256) void cvt_weights_kernel(const float* __restrict__ ipw,
    const float* __restrict__ opw, bf16_t* __restrict__ win, bf16_t* __restrict__ wout) {
  int i = blockIdx.x * 256 + threadIdx.x;
  const int n1 = DINPROJP * DMODEL;
  if (i < n1) {
    int row = i >> 9, col = i & (DMODEL - 1);
    float v = (row < DINPROJ) ? ipw[(size_t)row * DMODEL + col] : 0.f;
    win[i] = __float2bfloat16(v);
  } else {
    int j = i - n1;
    if (j < DMODEL * DINNER) wout[j] = __float2bfloat16(opw[j]);
  }
}

// ---------------- residual add + RMSNorm (512 cols), bf16 out ----------------
__global__ __launch_bounds__(128) void prenorm_kernel(const float* __restrict__ h,
    float* __restrict__ res, const float* __restrict__ w, bf16_t* __restrict__ xn) {
  int row = blockIdx.x;
  int tid = threadIdx.x;        // 128 threads, one float4 each (512 cols)
  const float4* h4 = (const float4*)(h + (size_t)row * DMODEL);
  float4* r4 = (float4*)(res + (size_t)row * DMODEL);
  float4 v = r4[tid];
  float4 a = h4[tid];
  v.x += a.x; v.y += a.y; v.z += a.z; v.w += a.w;
  r4[tid] = v;
  float ss = v.x * v.x + v.y * v.y + v.z * v.z + v.w * v.w;
  #pragma unroll
  for (int o = 32; o > 0; o >>= 1) ss += __shfl_down(ss, o);
  __shared__ float wred[2];
  if ((tid & 63) == 0) wred[tid >> 6] = ss;
  __syncthreads();
  float tot = wred[0] + wred[1];
  float scale = rsqrtf(tot / (float)DMODEL + EPSV);
  const float4* w4 = (const float4*)w;
  float4 wv = w4[tid];
  union { bf16_t b[4]; uint2 u; } pk;
  pk.b[0] = __float2bfloat16(v.x * scale * wv.x);
  pk.b[1] = __float2bfloat16(v.y * scale * wv.y);
  pk.b[2] = __float2bfloat16(v.z * scale * wv.z);
  pk.b[3] = __float2bfloat16(v.w * scale * wv.w);
  ((uint2*)(xn + (size_t)row * DMODEL))[tid] = pk.u;
}

// ---------------- bf16 MFMA GEMM: C[M,N] = A[M,K] * B[N,K]^T ----------------
// 128xBN tile, 4 waves; BN=128 -> wave 64x64 (4x4 frags), BN=64 -> wave 64x32 (4x2)
template<int BN>
__global__ __launch_bounds__(256) void gemm_bf16_bt(const bf16_t* __restrict__ A,
    const bf16_t* __restrict__ B, float* __restrict__ C, int M, int N, int K) {
  constexpr int JF = BN / 32;           // n-frags per wave
  __shared__ bf16_t As[128 * 32];
  __shared__ bf16_t Bs[BN * 32];
  int tid = threadIdx.x;
  int m0 = blockIdx.y * 128;
  int n0 = blockIdx.x * BN;
  int w = tid >> 6, lane = tid & 63;
  int wm = (w >> 1) * 64, wn = (w & 1) * (BN / 2);
  int l16 = lane & 15, lq = lane >> 4;
  floatx4 acc[4][JF];
  #pragma unroll
  for (int i = 0; i < 4; ++i)
    #pragma unroll
    for (int j = 0; j < JF; ++j)
      acc[i][j] = (floatx4){0.f, 0.f, 0.f, 0.f};
  int arow0 = tid >> 2, ak0 = (tid & 3) * 8;   // rows 0..63, k-seg 0..3
  const bf16_t* Abase = A + (size_t)m0 * K;
  const bf16_t* Bbase = B + (size_t)n0 * K;
  for (int k0 = 0; k0 < K; k0 += 32) {
    uint4 va0 = *(const uint4*)(Abase + (size_t)arow0 * K + k0 + ak0);
    uint4 va1 = *(const uint4*)(Abase + (size_t)(arow0 + 64) * K + k0 + ak0);
    uint4 vb0 = *(const uint4*)(Bbase + (size_t)arow0 * K + k0 + ak0);
    uint4 vb1;
    if (BN == 128) vb1 = *(const uint4*)(Bbase + (size_t)(arow0 + 64) * K + k0 + ak0);
    __syncthreads();
    *(uint4*)(As + tid * 8) = va0;
    *(uint4*)(As + (tid + 256) * 8) = va1;
    *(uint4*)(Bs + tid * 8) = vb0;
    if (BN == 128) *(uint4*)(Bs + (tid + 256) * 8) = vb1;
    __syncthreads();
    bf16x8 af[4], bfr[JF];
    #pragma unroll
    for (int i = 0; i < 4; ++i)
      af[i] = *(const bf16x8*)(As + (wm + i * 16 + l16) * 32 + lq * 8);
    #pragma unroll
    for (int j = 0; j < JF; ++j)
      bfr[j] = *(const bf16x8*)(Bs + (wn + j * 16 + l16) * 32 + lq * 8);
    #pragma unroll
    for (int i = 0; i < 4; ++i)
      #pragma unroll
      for (int j = 0; j < JF; ++j)
        acc[i][j] = __builtin_amdgcn_mfma_f32_16x16x32_bf16(af[i], bfr[j], acc[i][j], 0, 0, 0);
  }
  #pragma unroll
  for (int i = 0; i < 4; ++i) {
    #pragma unroll
    for (int j = 0; j < JF; ++j) {
      int n = n0 + wn + j * 16 + l16;
      if (n < N) {
        int mb = m0 + wm + i * 16 + lq * 4;
        #pragma unroll
        for (int r = 0; r < 4; ++r)
          C[(size_t)(mb + r) * N + n] = acc[i][j][r];
      }
    }
  }
}

// ---------------- fused causal conv (width 4) + silu + dt/dA ----------------
__global__ __launch_bounds__(320) void convdt_kernel(const float* __restrict__ zx,
    const float* __restrict__ cw, const float* __restrict__ cb,
    const float* __restrict__ dt_bias, const float* __restrict__ A_log,
    float* __restrict__ out, float* __restrict__ dt, float* __restrict__ dA) {
  int bl = blockIdx.x;                         // 0..NROWS-1
  int t = bl % SEQ;
  int tid = threadIdx.x;                       // 0..319
  int c = tid * 4;
  const float* base = zx + (size_t)bl * DINPROJ + DINNER + c;
  float4 acc = *(const float4*)(cb + c);
  #pragma unroll
  for (int k = 0; k < 4; ++k) {
    int tt = t + k - 3;
    if (tt >= 0) {
      float4 v = *(const float4*)(base + (ptrdiff_t)(k - 3) * DINPROJ);
      acc.x += v.x * cw[(c + 0) * 4 + k];
      acc.y += v.y * cw[(c + 1) * 4 + k];
      acc.z += v.z * cw[(c + 2) * 4 + k];
      acc.w += v.w * cw[(c + 3) * 4 + k];
    }
  }
  float4 o;
  o.x = siluf(acc.x); o.y = siluf(acc.y); o.z = siluf(acc.z); o.w = siluf(acc.w);
  *(float4*)(out + (size_t)bl * CONVDIM + c) = o;
  if (tid < NHEADS) {
    int h = tid;
    float v = zx[(size_t)bl * DINPROJ + (DINNER + CONVDIM) + h] + dt_bias[h];
    float sp = fmaxf(v, 0.f) + log1pf(expf(-fabsf(v)));
    float Ah = -expf(A_log[h]);
    dt[bl * NHEADS + h] = sp;
    dA[bl * NHEADS + h] = expf(sp * Ah);
  }
}

// ---------------- chunked SSD scan, pass 1: local scan from zero state ----------------
__global__ __launch_bounds__(256) void scan_local_kernel(const float* __restrict__ conv,
    const float* __restrict__ dtb, const float* __restrict__ dAb,
    const float* __restrict__ Dp, float* __restrict__ y,
    float* __restrict__ state, float* __restrict__ chunkprod) {
  int c = blockIdx.x;
  int bh = blockIdx.y;
  int b = bh >> 4, h = bh & 15;
  int tid = threadIdx.x;
  int s = tid >> 6;               // wave id: n-slice [32s, 32s+32)
  int p = tid & 63;               // lane = headdim index
  float hs[32];
  #pragma unroll
  for (int j = 0; j < 32; ++j) hs[j] = 0.f;
  float Dh = Dp[h];
  float prod = 1.f;
  __shared__ float yred[8][4][64];
  const int nbase = DINNER + s * 32;
  const int tstart = c * CH;
  for (int t0 = 0; t0 < CH; t0 += 8) {
    #pragma unroll 2
    for (int tc = 0; tc < 8; ++tc) {
      int t = tstart + t0 + tc;
      size_t rbase = (size_t)(b * SEQ + t) * CONVDIM;
      float x = conv[rbase + h * HEADDIM + p];
      int dti = (b * SEQ + t) * NHEADS + h;
      float dtv = dtb[dti];
      float dAv = dAb[dti];
      float dtx = dtv * x;
      prod *= dAv;
      const float4* Bp = (const float4*)(conv + rbase + nbase);
      const float4* Cp = (const float4*)(conv + rbase + nbase + DSTATE);
      float y0 = 0.f, y1 = 0.f, y2 = 0.f, y3 = 0.f;
      #pragma unroll
      for (int q = 0; q < 8; ++q) {
        float4 Bv = Bp[q];
        float4 Cv = Cp[q];
        hs[q * 4 + 0] = dAv * hs[q * 4 + 0] + dtx * Bv.x; y0 += hs[q * 4 + 0] * Cv.x;
        hs[q * 4 + 1] = dAv * hs[q * 4 + 1] + dtx * Bv.y; y1 += hs[q * 4 + 1] * Cv.y;
        hs[q * 4 + 2] = dAv * hs[q * 4 + 2] + dtx * Bv.z; y2 += hs[q * 4 + 2] * Cv.z;
        hs[q * 4 + 3] = dAv * hs[q * 4 + 3] + dtx * Bv.w; y3 += hs[q * 4 + 3] * Cv.w;
      }
      float yp = (y0 + y1) + (y2 + y3);
      if (s == 0) yp += Dh * x;
      yred[tc][s][p] = yp;
    }
    __syncthreads();
    for (int i = tid; i < 512; i += 256) {
      int tc = i >> 6, pp = i & 63;
      float v = yred[tc][0][pp] + yred[tc][1][pp] + yred[tc][2][pp] + yred[tc][3][pp];
      y[((size_t)(b * SEQ + t0 + tc + tstart) * NHEADS + h) * HEADDIM + pp] = v;
    }
    __syncthreads();
  }
  size_t sbase = ((size_t)bh * NCH + c) * STATESZ;
  #pragma unroll
  for (int j = 0; j < 32; ++j)
    state[sbase + (size_t)(s * 32 + j) * HEADDIM + p] = hs[j];
  if (tid == 0) chunkprod[bh * NCH + c] = prod;
}

// ---------------- pass 2 (fused combine): y[t] += cumA_incl[t] * (C_t . H_in) ----------------
// block for chunk c rebuilds H_in(c) from raw end-states of chunks 0..c-1
__global__ __launch_bounds__(256) void ycorr_kernel(const float* __restrict__ conv,
    const float* __restrict__ dAb, const float* __restrict__ state,
    const float* __restrict__ cprod, float* __restrict__ y) {
  int c = blockIdx.x + 1;
  int bh = blockIdx.y;
  int b = bh >> 4, h = bh & 15;
  int tid = threadIdx.x;
  __shared__ float hlds[STATESZ];   // [n][p] layout, bank=p%32 -> 2-way (free)
  __shared__ float cA[CH];
  // --- combine: H = P_c' * H + S(c'), c' ascending (same order as old kernel) ---
  float4 H[8];
  #pragma unroll
  for (int q = 0; q < 8; ++q) H[q] = make_float4(0.f, 0.f, 0.f, 0.f);
  const float4* slab = (const float4*)(state + (size_t)bh * NCH * STATESZ);
  for (int cp = 0; cp < c; ++cp) {
    float P = cprod[bh * NCH + cp];
    const float4* sp = slab + (size_t)cp * (STATESZ / 4);
    #pragma unroll
    for (int q = 0; q < 8; ++q) {
      float4 S = sp[q * 256 + tid];          // coalesced
      H[q].x = P * H[q].x + S.x; H[q].y = P * H[q].y + S.y;
      H[q].z = P * H[q].z + S.z; H[q].w = P * H[q].w + S.w;
    }
  }
  float4* hl4 = (float4*)hlds;
  #pragma unroll
  for (int q = 0; q < 8; ++q) hl4[q * 256 + tid] = H[q];
  const int tstart = c * CH;
  if (tid < CH) cA[tid] = dAb[(b * SEQ + tstart + tid) * NHEADS + h];
  __syncthreads();
  // inclusive product scan over cA
  for (int off = 1; off < CH; off <<= 1) {
    float tmp = 1.f;
    if (tid < CH && tid >= off) tmp = cA[tid - off];
    __syncthreads();
    if (tid < CH) cA[tid] *= tmp;
    __syncthreads();
  }
  int s = tid >> 6, p = tid & 63;
  float acc[CH / 4];
  #pragma unroll
  for (int i = 0; i < CH / 4; ++i) acc[i] = 0.f;
  const float* Cbase = conv + (size_t)(b * SEQ + tstart) * CONVDIM + DINNER + DSTATE;
  for (int nq = 0; nq < DSTATE / 4; ++nq) {
    float h0 = hlds[(nq * 4 + 0) * HEADDIM + p];
    float h1 = hlds[(nq * 4 + 1) * HEADDIM + p];
    float h2 = hlds[(nq * 4 + 2) * HEADDIM + p];
    float h3 = hlds[(nq * 4 + 3) * HEADDIM + p];
    #pragma unroll
    for (int i = 0; i < CH / 4; ++i) {
      int tt = s + i * 4;
      float4 Cv = *(const float4*)(Cbase + (size_t)tt * CONVDIM + nq * 4);
      acc[i] += Cv.x * h0 + Cv.y * h1 + Cv.z * h2 + Cv.w * h3;
    }
  }
  #pragma unroll
  for (int i = 0; i < CH / 4; ++i) {
    int tt = s + i * 4;
    size_t yi = ((size_t)(b * SEQ + tstart + tt) * NHEADS + h) * HEADDIM + p;
    y[yi] += cA[tt] * acc[i];
  }
}

// ---------------- gated RMSNorm over 1024, bf16 out ----------------
__global__ __launch_bounds__(256) void gated_norm_kernel(const float* __restrict__ y,
    const float* __restrict__ zx, const float* __restrict__ gw, bf16_t* __restrict__ out) {
  int row = blockIdx.x;
  int tid = threadIdx.x;
  const float4* y4 = (const float4*)(y + (size_t)row * DINNER);
  const float4* z4 = (const float4*)(zx + (size_t)row * DINPROJ);
  float4 yv = y4[tid];
  float4 zv = z4[tid];
  float4 g;
  g.x = yv.x * siluf(zv.x); g.y = yv.y * siluf(zv.y);
  g.z = yv.z * siluf(zv.z); g.w = yv.w * siluf(zv.w);
  float ss = g.x * g.x + g.y * g.y + g.z * g.z + g.w * g.w;
  #pragma unroll
  for (int o = 32; o > 0; o >>= 1) ss += __shfl_down(ss, o);
  __shared__ float red[4];
  if ((tid & 63) == 0) red[tid >> 6] = ss;
  __syncthreads();
  float tot = red[0] + red[1] + red[2] + red[3];
  float scale = rsqrtf(tot / (float)DINNER + EPSV);
  const float4* g4 = (const float4*)gw;
  float4 wv = g4[tid];
  union { bf16_t b[4]; uint2 u; } pk;
  pk.b[0] = __float2bfloat16(g.x * scale * wv.x);
  pk.b[1] = __float2bfloat16(g.y * scale * wv.y);
  pk.b[2] = __float2bfloat16(g.z * scale * wv.z);
  pk.b[3] = __float2bfloat16(g.w * scale * wv.w);
  ((uint2*)(out + (size_t)row * DINNER))[tid] = pk.u;
}

// ---------------- per-row loss: lse - logit[target] ----------------
__global__ __launch_bounds__(256) void rowloss_kernel(const float* __restrict__ logits,
    const int* __restrict__ targets, float* __restrict__ rl) {
  int row = blockIdx.x * 4 + (threadIdx.x >> 6);
  int lane = threadIdx.x & 63;
  const float* lr = logits + (size_t)row * VOCABSZ;
  float4 v = ((const float4*)lr)[lane];
  float mx = fmaxf(fmaxf(v.x, v.y), fmaxf(v.z, v.w));
  #pragma unroll
  for (int o = 32; o > 0; o >>= 1) mx = fmaxf(mx, __shfl_down(mx, o));
  mx = __shfl(mx, 0);
  float e = expf(v.x - mx) + expf(v.y - mx) + expf(v.z - mx) + expf(v.w - mx);
  #pragma unroll
  for (int o = 32; o > 0; o >>= 1) e += __shfl_down(e, o);
  if (lane == 0) {
    float lse = logf(e) + mx;
    rl[row] = lse - lr[targets[row]];
  }
}

__global__ __launch_bounds__(256) void loss_reduce_kernel(const float* __restrict__ rl,
    float* __restrict__ out) {
  int tid = threadIdx.x;
  float ssum = 0.f;
  for (int i = tid; i < NROWS; i += 256) ssum += rl[i];
  #pragma unroll
  for (int o = 32; o > 0; o >>= 1) ssum += __shfl_down(ssum, o);
  __shared__ float red[4];
  if ((tid & 63) == 0) red[tid >> 6] = ssum;
  __syncthreads();
  if (tid == 0) out[0] = (red[0] + red[1] + red[2] + red[3]) / (float)NROWS;
}

extern "C" void kernel_launch(void* const* d_in, const int* in_sizes, int n_in,
                              void* d_out, int out_size, void* d_ws, size_t ws_size,
                              hipStream_t stream) {
  const int*   tokens       = (const int*)d_in[0];
  const int*   targets      = (const int*)d_in[1];
  const float* embedding    = (const float*)d_in[2];
  const float* in_proj_w    = (const float*)d_in[3];
  const float* conv_w       = (const float*)d_in[4];
  const float* conv_b       = (const float*)d_in[5];
  const float* dt_bias      = (const float*)d_in[6];
  const float* A_log        = (const float*)d_in[7];
  const float* Dp           = (const float*)d_in[8];
  const float* gnorm_w      = (const float*)d_in[9];
  const float* out_proj_w   = (const float*)d_in[10];
  const float* block_norm_w = (const float*)d_in[11];
  const float* norm_f_w     = (const float*)d_in[12];
  float* out = (float*)d_out;

  float* ws = (float*)d_ws;
  size_t off = 0;
  float* hidden   = ws + off; off += (size_t)NROWS * DMODEL;
  float* residual = ws + off; off += (size_t)NROWS * DMODEL;
  float* zx       = ws + off; off += (size_t)NROWS * DINPROJ;
  float* convo    = ws + off; off += (size_t)NROWS * CONVDIM;
  float* dtb      = ws + off; off += (size_t)NROWS * NHEADS;
  float* dAb      = ws + off; off += (size_t)NROWS * NHEADS;
  float* ybuf     = ws + off; off += (size_t)NROWS * DINNER;
  float* cprod    = ws + off; off += (size_t)BATCH * NHEADS * NCH;
  float* rowloss  = ws + off; off += NROWS;
  bf16_t* w_in_bf  = (bf16_t*)(ws + off); off += (size_t)DINPROJP * DMODEL / 2;
  bf16_t* w_out_bf = (bf16_t*)(ws + off); off += (size_t)DMODEL * DINNER / 2;
  bf16_t* w_emb_bf = (bf16_t*)(ws + off); off += (size_t)VOCABSZ * DMODEL / 2;
  // union region: state (16.78M floats) vs bf16 activations (disjoint live ranges)
  float*  state  = ws + off;
  bf16_t* xn_bf  = (bf16_t*)(ws + off);   // live prenorm -> gemm1
  bf16_t* yn_bf  = (bf16_t*)(ws + off);   // live gated_norm -> gemm2
  off += (size_t)BATCH * NHEADS * NCH * STATESZ;

  embed_kernel<<<(NROWS * DMODEL + VOCABSZ * DMODEL) / 256, 256, 0, stream>>>(
      tokens, embedding, hidden, residual, w_emb_bf);

  const int cvt_total = DINPROJP * DMODEL + DMODEL * DINNER;
  for (int l = 0; l < NLAYER; ++l) {
    const float* ipw = in_proj_w + (size_t)l * DINPROJ * DMODEL;
    const float* cw  = conv_w + (size_t)l * CONVDIM * 4;
    const float* cb  = conv_b + (size_t)l * CONVDIM;
    const float* dtbias_l = dt_bias + (size_t)l * NHEADS;
    const float* alog_l   = A_log + (size_t)l * NHEADS;
    const float* D_l      = Dp + (size_t)l * NHEADS;
    const float* gw  = gnorm_w + (size_t)l * DINNER;
    const float* opw = out_proj_w + (size_t)l * DMODEL * DINNER;
    const float* bnw = block_norm_w + (size_t)l * DMODEL;

    cvt_weights_kernel<<<(cvt_total + 255) / 256, 256, 0, stream>>>(ipw, opw, w_in_bf, w_out_bf);
    prenorm_kernel<<<NROWS, 128, 0, stream>>>(hidden, residual, bnw, xn_bf);
    dim3 g1(DINPROJP / 128, NROWS / 128);
    gemm_bf16_bt<128><<<g1, 256, 0, stream>>>(xn_bf, w_in_bf, zx, NROWS, DINPROJ, DMODEL);
    convdt_kernel<<<NROWS, 320, 0, stream>>>(zx, cw, cb, dtbias_l, alog_l, convo, dtb, dAb);
    scan_local_kernel<<<dim3(NCH, BATCH * NHEADS), 256, 0, stream>>>(
        convo, dtb, dAb, D_l, ybuf, state, cprod);
    ycorr_kernel<<<dim3(NCH - 1, BATCH * NHEADS), 256, 0, stream>>>(
        convo, dAb, state, cprod, ybuf);
    gated_norm_kernel<<<NROWS, 256, 0, stream>>>(ybuf, zx, gw, yn_bf);
    dim3 g2(DMODEL / 64, NROWS / 128);
    gemm_bf16_bt<64><<<g2, 256, 0, stream>>>(yn_bf, w_out_bf, hidden, NROWS, DMODEL, DINNER);
  }

  prenorm_kernel<<<NROWS, 128, 0, stream>>>(hidden, residual, norm_f_w, xn_bf);
  dim3 g3(VOCABSZ / 64, NROWS / 128);
  gemm_bf16_bt<64><<<g3, 256, 0, stream>>>(xn_bf, w_emb_bf, out, NROWS, VOCABSZ, DMODEL);
  rowloss_kernel<<<NROWS / 4, 256, 0, stream>>>(out, targets, rowloss);
  loss_reduce_kernel<<<1, 256, 0, stream>>>(rowloss, out + (size_t)(out_size - 1));
}

// Round 6
// 18961.006 us; speedup vs baseline: 2.3761x; 1.3655x over previous
//
#include <hip/hip_runtime.h>
#include <hip/hip_bf16.h>
#include <math.h>

#define BATCH   16
#define SEQ     768
#define DMODEL  512
#define DSTATE  128
#define DINNER  1024
#define NHEADS  16
#define HEADDIM 64
#define CONVDIM 1280            // DINNER + 2*DSTATE
#define DINPROJ 2320            // 2*DINNER + 2*DSTATE + NHEADS
#define DINPROJP 2432           // padded to multiple of 128 for GEMM tiles
#define NLAYER  28
#define VOCABSZ 256
#define NROWS   (BATCH*SEQ)     // 12288
#define EPSV    1e-5f
#define NCH     8               // chunks per sequence
#define CH      96              // SEQ / NCH
#define STATESZ (HEADDIM*DSTATE) // 8192 floats per (b,h,chunk)

typedef __hip_bfloat16 bf16_t;
typedef __attribute__((ext_vector_type(8))) __bf16 bf16x8;
typedef __attribute__((ext_vector_type(4))) float floatx4;

__device__ __forceinline__ float siluf(float v) { return v / (1.f + expf(-v)); }

// ---------------- embed + residual zero + embedding bf16 cvt, one dispatch ----------------
__global__ __launch_bounds__(256) void embed_kernel(const int* __restrict__ tok,
    const float* __restrict__ emb, float* __restrict__ hid, float* __restrict__ res,
    bf16_t* __restrict__ w_emb_bf) {
  int i = blockIdx.x * 256 + threadIdx.x;
  const int total = NROWS * DMODEL;
  if (i < total) {
    int r = i >> 9;               // / DMODEL
    int d = i & (DMODEL - 1);
    hid[i] = emb[(size_t)tok[r] * DMODEL + d];
    res[i] = 0.f;
  } else {
    int j = i - total;
    if (j < VOCABSZ * DMODEL) w_emb_bf[j] = __float2bfloat16(emb[j]);
  }
}

// ---------------- per-layer weight conversion, one dispatch ----------------
__global__ __launch_bounds__(256) void cvt_weights_kernel(const float* __restrict__ ipw,
    const float* __restrict__ opw, bf16_t* __restrict__ win, bf16_t* __restrict__ wout) {
  int i = blockIdx.x * 256 + threadIdx.x;
  const int n1 = DINPROJP * DMODEL;
  if (i < n1) {
    int row = i >> 9, col = i & (DMODEL - 1);
    float v = (row < DINPROJ) ? ipw[(size_t)row * DMODEL + col] : 0.f;
    win[i] = __float2bfloat16(v);
  } else {
    int j = i - n1;
    if (j < DMODEL * DINNER) wout[j] = __float2bfloat16(opw[j]);
  }
}

// ---------------- residual add + RMSNorm (512 cols), bf16 out ----------------
__global__ __launch_bounds__(128) void prenorm_kernel(const float* __restrict__ h,
    float* __restrict__ res, const float* __restrict__ w, bf16_t* __restrict__ xn) {
  int row = blockIdx.x;
  int tid = threadIdx.x;        // 128 threads, one float4 each (512 cols)
  const float4* h4 = (const float4*)(h + (size_t)row * DMODEL);
  float4* r4 = (float4*)(res + (size_t)row * DMODEL);
  float4 v = r4[tid];
  float4 a = h4[tid];
  v.x += a.x; v.y += a.y; v.z += a.z; v.w += a.w;
  r4[tid] = v;
  float ss = v.x * v.x + v.y * v.y + v.z * v.z + v.w * v.w;
  #pragma unroll
  for (int o = 32; o > 0; o >>= 1) ss += __shfl_down(ss, o);
  __shared__ float wred[2];
  if ((tid & 63) == 0) wred[tid >> 6] = ss;
  __syncthreads();
  float tot = wred[0] + wred[1];
  float scale = rsqrtf(tot / (float)DMODEL + EPSV);
  const float4* w4 = (const float4*)w;
  float4 wv = w4[tid];
  union { bf16_t b[4]; uint2 u; } pk;
  pk.b[0] = __float2bfloat16(v.x * scale * wv.x);
  pk.b[1] = __float2bfloat16(v.y * scale * wv.y);
  pk.b[2] = __float2bfloat16(v.z * scale * wv.z);
  pk.b[3] = __float2bfloat16(v.w * scale * wv.w);
  ((uint2*)(xn + (size_t)row * DMODEL))[tid] = pk.u;
}

// ---------------- bf16 MFMA GEMM: C[M,N] = A[M,K] * B[N,K]^T ----------------
// 128xBN tile, 4 waves; BN=128 -> wave 64x64 (4x4 frags), BN=64 -> wave 64x32 (4x2)
template<int BN>
__global__ __launch_bounds__(256) void gemm_bf16_bt(const bf16_t* __restrict__ A,
    const bf16_t* __restrict__ B, float* __restrict__ C, int M, int N, int K) {
  constexpr int JF = BN / 32;           // n-frags per wave
  __shared__ bf16_t As[128 * 32];
  __shared__ bf16_t Bs[BN * 32];
  int tid = threadIdx.x;
  int m0 = blockIdx.y * 128;
  int n0 = blockIdx.x * BN;
  int w = tid >> 6, lane = tid & 63;
  int wm = (w >> 1) * 64, wn = (w & 1) * (BN / 2);
  int l16 = lane & 15, lq = lane >> 4;
  floatx4 acc[4][JF];
  #pragma unroll
  for (int i = 0; i < 4; ++i)
    #pragma unroll
    for (int j = 0; j < JF; ++j)
      acc[i][j] = (floatx4){0.f, 0.f, 0.f, 0.f};
  int arow0 = tid >> 2, ak0 = (tid & 3) * 8;   // rows 0..63, k-seg 0..3
  const bf16_t* Abase = A + (size_t)m0 * K;
  const bf16_t* Bbase = B + (size_t)n0 * K;
  for (int k0 = 0; k0 < K; k0 += 32) {
    uint4 va0 = *(const uint4*)(Abase + (size_t)arow0 * K + k0 + ak0);
    uint4 va1 = *(const uint4*)(Abase + (size_t)(arow0 + 64) * K + k0 + ak0);
    uint4 vb0 = *(const uint4*)(Bbase + (size_t)arow0 * K + k0 + ak0);
    uint4 vb1;
    if (BN == 128) vb1 = *(const uint4*)(Bbase + (size_t)(arow0 + 64) * K + k0 + ak0);
    __syncthreads();
    *(uint4*)(As + tid * 8) = va0;
    *(uint4*)(As + (tid + 256) * 8) = va1;
    *(uint4*)(Bs + tid * 8) = vb0;
    if (BN == 128) *(uint4*)(Bs + (tid + 256) * 8) = vb1;
    __syncthreads();
    bf16x8 af[4], bfr[JF];
    #pragma unroll
    for (int i = 0; i < 4; ++i)
      af[i] = *(const bf16x8*)(As + (wm + i * 16 + l16) * 32 + lq * 8);
    #pragma unroll
    for (int j = 0; j < JF; ++j)
      bfr[j] = *(const bf16x8*)(Bs + (wn + j * 16 + l16) * 32 + lq * 8);
    #pragma unroll
    for (int i = 0; i < 4; ++i)
      #pragma unroll
      for (int j = 0; j < JF; ++j)
        acc[i][j] = __builtin_amdgcn_mfma_f32_16x16x32_bf16(af[i], bfr[j], acc[i][j], 0, 0, 0);
  }
  #pragma unroll
  for (int i = 0; i < 4; ++i) {
    #pragma unroll
    for (int j = 0; j < JF; ++j) {
      int n = n0 + wn + j * 16 + l16;
      if (n < N) {
        int mb = m0 + wm + i * 16 + lq * 4;
        #pragma unroll
        for (int r = 0; r < 4; ++r)
          C[(size_t)(mb + r) * N + n] = acc[i][j][r];
      }
    }
  }
}

// ---------------- fused causal conv (width 4) + silu + dt/dA ----------------
__global__ __launch_bounds__(320) void convdt_kernel(const float* __restrict__ zx,
    const float* __restrict__ cw, const float* __restrict__ cb,
    const float* __restrict__ dt_bias, const float* __restrict__ A_log,
    float* __restrict__ out, float* __restrict__ dt, float* __restrict__ dA) {
  int bl = blockIdx.x;                         // 0..NROWS-1
  int t = bl % SEQ;
  int tid = threadIdx.x;                       // 0..319
  int c = tid * 4;
  const float* base = zx + (size_t)bl * DINPROJ + DINNER + c;
  float4 acc = *(const float4*)(cb + c);
  #pragma unroll
  for (int k = 0; k < 4; ++k) {
    int tt = t + k - 3;
    if (tt >= 0) {
      float4 v = *(const float4*)(base + (ptrdiff_t)(k - 3) * DINPROJ);
      acc.x += v.x * cw[(c + 0) * 4 + k];
      acc.y += v.y * cw[(c + 1) * 4 + k];
      acc.z += v.z * cw[(c + 2) * 4 + k];
      acc.w += v.w * cw[(c + 3) * 4 + k];
    }
  }
  float4 o;
  o.x = siluf(acc.x); o.y = siluf(acc.y); o.z = siluf(acc.z); o.w = siluf(acc.w);
  *(float4*)(out + (size_t)bl * CONVDIM + c) = o;
  if (tid < NHEADS) {
    int h = tid;
    float v = zx[(size_t)bl * DINPROJ + (DINNER + CONVDIM) + h] + dt_bias[h];
    float sp = fmaxf(v, 0.f) + log1pf(expf(-fabsf(v)));
    float Ah = -expf(A_log[h]);
    dt[bl * NHEADS + h] = sp;
    dA[bl * NHEADS + h] = expf(sp * Ah);
  }
}

// ---------------- chunked SSD scan, pass 1: LDS-staged local scan ----------------
// per 8-timestep group: block cooperatively stages B|C (8x256), x (8x64), dt/dA (16)
// into LDS with coalesced loads; register-prefetch of group g+1 overlaps compute of g.
__global__ __launch_bounds__(256) void scan_local_kernel(const float* __restrict__ conv,
    const float* __restrict__ dtb, const float* __restrict__ dAb,
    const float* __restrict__ Dp, float* __restrict__ y,
    float* __restrict__ state, float* __restrict__ chunkprod) {
  int c = blockIdx.x;
  int bh = blockIdx.y;
  int b = bh >> 4, h = bh & 15;
  int tid = threadIdx.x;
  int s = tid >> 6;               // wave id: n-slice [32s, 32s+32)
  int p = tid & 63;               // lane = headdim index
  float hs[32];
  #pragma unroll
  for (int j = 0; j < 32; ++j) hs[j] = 0.f;
  float Dh = Dp[h];
  float prod = 1.f;
  __shared__ float BC[8][256];    // [tc][0..127]=B, [128..255]=C
  __shared__ float xs[8][64];
  __shared__ float dtA[16];       // [0..7]=dt, [8..15]=dA
  __shared__ float yred[8][4][64];
  const int tstart = c * CH;
  const size_t row0 = (size_t)(b * SEQ + tstart);

  // staging index precompute
  int i0 = tid, i1 = tid + 256;                 // BC float4 slots
  int bct0 = i0 >> 6, bco0 = (i0 & 63) * 4;
  int bct1 = i1 >> 6, bco1 = (i1 & 63) * 4;
  int xt = tid >> 4, xo = (tid & 15) * 4;       // xs float4 slots (tid<128)

  float4 r0, r1, rx = make_float4(0.f, 0.f, 0.f, 0.f);
  float rsc = 0.f;
  {
    // prologue: load group 0
    size_t rb = row0 * CONVDIM + DINNER;
    r0 = *(const float4*)(conv + rb + (size_t)bct0 * CONVDIM + bco0);
    r1 = *(const float4*)(conv + rb + (size_t)bct1 * CONVDIM + bco1);
    if (tid < 128) rx = *(const float4*)(conv + (row0 + xt) * CONVDIM + h * HEADDIM + xo);
    else if (tid < 136) rsc = dtb[(row0 + (tid - 128)) * NHEADS + h];
    else if (tid < 144) rsc = dAb[(row0 + (tid - 136)) * NHEADS + h];
  }

  for (int g = 0; g < CH / 8; ++g) {
    __syncthreads();              // previous iteration's LDS readers done
    *(float4*)&BC[bct0][bco0] = r0;
    *(float4*)&BC[bct1][bco1] = r1;
    if (tid < 128) *(float4*)&xs[xt][xo] = rx;
    else if (tid < 144) dtA[tid - 128] = rsc;
    __syncthreads();
    if (g + 1 < CH / 8) {
      size_t rb = (row0 + (g + 1) * 8) * CONVDIM + DINNER;
      r0 = *(const float4*)(conv + rb + (size_t)bct0 * CONVDIM + bco0);
      r1 = *(const float4*)(conv + rb + (size_t)bct1 * CONVDIM + bco1);
      if (tid < 128) rx = *(const float4*)(conv + (row0 + (g + 1) * 8 + xt) * CONVDIM + h * HEADDIM + xo);
      else if (tid < 136) rsc = dtb[(row0 + (g + 1) * 8 + (tid - 128)) * NHEADS + h];
      else if (tid < 144) rsc = dAb[(row0 + (g + 1) * 8 + (tid - 136)) * NHEADS + h];
    }
    #pragma unroll
    for (int tc = 0; tc < 8; ++tc) {
      float x = xs[tc][p];
      float dtv = dtA[tc];
      float dAv = dtA[8 + tc];
      float dtx = dtv * x;
      prod *= dAv;
      const float4* Bq = (const float4*)&BC[tc][s * 32];
      const float4* Cq = (const float4*)&BC[tc][128 + s * 32];
      float y0 = 0.f, y1 = 0.f, y2 = 0.f, y3 = 0.f;
      #pragma unroll
      for (int q = 0; q < 8; ++q) {
        float4 Bv = Bq[q];
        float4 Cv = Cq[q];
        hs[q * 4 + 0] = dAv * hs[q * 4 + 0] + dtx * Bv.x; y0 += hs[q * 4 + 0] * Cv.x;
        hs[q * 4 + 1] = dAv * hs[q * 4 + 1] + dtx * Bv.y; y1 += hs[q * 4 + 1] * Cv.y;
        hs[q * 4 + 2] = dAv * hs[q * 4 + 2] + dtx * Bv.z; y2 += hs[q * 4 + 2] * Cv.z;
        hs[q * 4 + 3] = dAv * hs[q * 4 + 3] + dtx * Bv.w; y3 += hs[q * 4 + 3] * Cv.w;
      }
      float yp = (y0 + y1) + (y2 + y3);
      if (s == 0) yp += Dh * x;
      yred[tc][s][p] = yp;
    }
    __syncthreads();
    for (int i = tid; i < 512; i += 256) {
      int tc = i >> 6, pp = i & 63;
      float v = yred[tc][0][pp] + yred[tc][1][pp] + yred[tc][2][pp] + yred[tc][3][pp];
      y[((size_t)(row0 + g * 8 + tc) * NHEADS + h) * HEADDIM + pp] = v;
    }
  }
  size_t sbase = ((size_t)bh * NCH + c) * STATESZ;
  #pragma unroll
  for (int j = 0; j < 32; ++j)
    state[sbase + (size_t)(s * 32 + j) * HEADDIM + p] = hs[j];
  if (tid == 0) chunkprod[bh * NCH + c] = prod;
}

// ---------------- pass 2 (fused combine): y[t] += cumA_incl[t] * (C_t . H_in) ----------------
__global__ __launch_bounds__(256) void ycorr_kernel(const float* __restrict__ conv,
    const float* __restrict__ dAb, const float* __restrict__ state,
    const float* __restrict__ cprod, float* __restrict__ y) {
  int c = blockIdx.x + 1;
  int bh = blockIdx.y;
  int b = bh >> 4, h = bh & 15;
  int tid = threadIdx.x;
  __shared__ float hlds[STATESZ];   // [n][p] layout, bank=p%32 -> 2-way (free)
  __shared__ float cA[CH];
  float4 H[8];
  #pragma unroll
  for (int q = 0; q < 8; ++q) H[q] = make_float4(0.f, 0.f, 0.f, 0.f);
  const float4* slab = (const float4*)(state + (size_t)bh * NCH * STATESZ);
  for (int cp = 0; cp < c; ++cp) {
    float P = cprod[bh * NCH + cp];
    const float4* sp = slab + (size_t)cp * (STATESZ / 4);
    #pragma unroll
    for (int q = 0; q < 8; ++q) {
      float4 S = sp[q * 256 + tid];          // coalesced
      H[q].x = P * H[q].x + S.x; H[q].y = P * H[q].y + S.y;
      H[q].z = P * H[q].z + S.z; H[q].w = P * H[q].w + S.w;
    }
  }
  float4* hl4 = (float4*)hlds;
  #pragma unroll
  for (int q = 0; q < 8; ++q) hl4[q * 256 + tid] = H[q];
  const int tstart = c * CH;
  if (tid < CH) cA[tid] = dAb[(b * SEQ + tstart + tid) * NHEADS + h];
  __syncthreads();
  for (int off = 1; off < CH; off <<= 1) {
    float tmp = 1.f;
    if (tid < CH && tid >= off) tmp = cA[tid - off];
    __syncthreads();
    if (tid < CH) cA[tid] *= tmp;
    __syncthreads();
  }
  int s = tid >> 6, p = tid & 63;
  float acc[CH / 4];
  #pragma unroll
  for (int i = 0; i < CH / 4; ++i) acc[i] = 0.f;
  const float* Cbase = conv + (size_t)(b * SEQ + tstart) * CONVDIM + DINNER + DSTATE;
  for (int nq = 0; nq < DSTATE / 4; ++nq) {
    float h0 = hlds[(nq * 4 + 0) * HEADDIM + p];
    float h1 = hlds[(nq * 4 + 1) * HEADDIM + p];
    float h2 = hlds[(nq * 4 + 2) * HEADDIM + p];
    float h3 = hlds[(nq * 4 + 3) * HEADDIM + p];
    #pragma unroll
    for (int i = 0; i < CH / 4; ++i) {
      int tt = s + i * 4;
      float4 Cv = *(const float4*)(Cbase + (size_t)tt * CONVDIM + nq * 4);
      acc[i] += Cv.x * h0 + Cv.y * h1 + Cv.z * h2 + Cv.w * h3;
    }
  }
  #pragma unroll
  for (int i = 0; i < CH / 4; ++i) {
    int tt = s + i * 4;
    size_t yi = ((size_t)(b * SEQ + tstart + tt) * NHEADS + h) * HEADDIM + p;
    y[yi] += cA[tt] * acc[i];
  }
}

// ---------------- gated RMSNorm over 1024, bf16 out ----------------
__global__ __launch_bounds__(256) void gated_norm_kernel(const float* __restrict__ y,
    const float* __restrict__ zx, const float* __restrict__ gw, bf16_t* __restrict__ out) {
  int row = blockIdx.x;
  int tid = threadIdx.x;
  const float4* y4 = (const float4*)(y + (size_t)row * DINNER);
  const float4* z4 = (const float4*)(zx + (size_t)row * DINPROJ);
  float4 yv = y4[tid];
  float4 zv = z4[tid];
  float4 g;
  g.x = yv.x * siluf(zv.x); g.y = yv.y * siluf(zv.y);
  g.z = yv.z * siluf(zv.z); g.w = yv.w * siluf(zv.w);
  float ss = g.x * g.x + g.y * g.y + g.z * g.z + g.w * g.w;
  #pragma unroll
  for (int o = 32; o > 0; o >>= 1) ss += __shfl_down(ss, o);
  __shared__ float red[4];
  if ((tid & 63) == 0) red[tid >> 6] = ss;
  __syncthreads();
  float tot = red[0] + red[1] + red[2] + red[3];
  float scale = rsqrtf(tot / (float)DINNER + EPSV);
  const float4* g4 = (const float4*)gw;
  float4 wv = g4[tid];
  union { bf16_t b[4]; uint2 u; } pk;
  pk.b[0] = __float2bfloat16(g.x * scale * wv.x);
  pk.b[1] = __float2bfloat16(g.y * scale * wv.y);
  pk.b[2] = __float2bfloat16(g.z * scale * wv.z);
  pk.b[3] = __float2bfloat16(g.w * scale * wv.w);
  ((uint2*)(out + (size_t)row * DINNER))[tid] = pk.u;
}

// ---------------- per-row loss: lse - logit[target] ----------------
__global__ __launch_bounds__(256) void rowloss_kernel(const float* __restrict__ logits,
    const int* __restrict__ targets, float* __restrict__ rl) {
  int row = blockIdx.x * 4 + (threadIdx.x >> 6);
  int lane = threadIdx.x & 63;
  const float* lr = logits + (size_t)row * VOCABSZ;
  float4 v = ((const float4*)lr)[lane];
  float mx = fmaxf(fmaxf(v.x, v.y), fmaxf(v.z, v.w));
  #pragma unroll
  for (int o = 32; o > 0; o >>= 1) mx = fmaxf(mx, __shfl_down(mx, o));
  mx = __shfl(mx, 0);
  float e = expf(v.x - mx) + expf(v.y - mx) + expf(v.z - mx) + expf(v.w - mx);
  #pragma unroll
  for (int o = 32; o > 0; o >>= 1) e += __shfl_down(e, o);
  if (lane == 0) {
    float lse = logf(e) + mx;
    rl[row] = lse - lr[targets[row]];
  }
}

__global__ __launch_bounds__(256) void loss_reduce_kernel(const float* __restrict__ rl,
    float* __restrict__ out) {
  int tid = threadIdx.x;
  float ssum = 0.f;
  for (int i = tid; i < NROWS; i += 256) ssum += rl[i];
  #pragma unroll
  for (int o = 32; o > 0; o >>= 1) ssum += __shfl_down(ssum, o);
  __shared__ float red[4];
  if ((tid & 63) == 0) red[tid >> 6] = ssum;
  __syncthreads();
  if (tid == 0) out[0] = (red[0] + red[1] + red[2] + red[3]) / (float)NROWS;
}

extern "C" void kernel_launch(void* const* d_in, const int* in_sizes, int n_in,
                              void* d_out, int out_size, void* d_ws, size_t ws_size,
                              hipStream_t stream) {
  const int*   tokens       = (const int*)d_in[0];
  const int*   targets      = (const int*)d_in[1];
  const float* embedding    = (const float*)d_in[2];
  const float* in_proj_w    = (const float*)d_in[3];
  const float* conv_w       = (const float*)d_in[4];
  const float* conv_b       = (const float*)d_in[5];
  const float* dt_bias      = (const float*)d_in[6];
  const float* A_log        = (const float*)d_in[7];
  const float* Dp           = (const float*)d_in[8];
  const float* gnorm_w      = (const float*)d_in[9];
  const float* out_proj_w   = (const float*)d_in[10];
  const float* block_norm_w = (const float*)d_in[11];
  const float* norm_f_w     = (const float*)d_in[12];
  float* out = (float*)d_out;

  float* ws = (float*)d_ws;
  size_t off = 0;
  float* hidden   = ws + off; off += (size_t)NROWS * DMODEL;
  float* residual = ws + off; off += (size_t)NROWS * DMODEL;
  float* zx       = ws + off; off += (size_t)NROWS * DINPROJ;
  float* convo    = ws + off; off += (size_t)NROWS * CONVDIM;
  float* dtb      = ws + off; off += (size_t)NROWS * NHEADS;
  float* dAb      = ws + off; off += (size_t)NROWS * NHEADS;
  float* ybuf     = ws + off; off += (size_t)NROWS * DINNER;
  float* cprod    = ws + off; off += (size_t)BATCH * NHEADS * NCH;
  float* rowloss  = ws + off; off += NROWS;
  bf16_t* w_in_bf  = (bf16_t*)(ws + off); off += (size_t)DINPROJP * DMODEL / 2;
  bf16_t* w_out_bf = (bf16_t*)(ws + off); off += (size_t)DMODEL * DINNER / 2;
  bf16_t* w_emb_bf = (bf16_t*)(ws + off); off += (size_t)VOCABSZ * DMODEL / 2;
  // union region: state (16.78M floats) vs bf16 activations (disjoint live ranges)
  float*  state  = ws + off;
  bf16_t* xn_bf  = (bf16_t*)(ws + off);   // live prenorm -> gemm1
  bf16_t* yn_bf  = (bf16_t*)(ws + off);   // live gated_norm -> gemm2
  off += (size_t)BATCH * NHEADS * NCH * STATESZ;

  embed_kernel<<<(NROWS * DMODEL + VOCABSZ * DMODEL) / 256, 256, 0, stream>>>(
      tokens, embedding, hidden, residual, w_emb_bf);

  const int cvt_total = DINPROJP * DMODEL + DMODEL * DINNER;
  for (int l = 0; l < NLAYER; ++l) {
    const float* ipw = in_proj_w + (size_t)l * DINPROJ * DMODEL;
    const float* cw  = conv_w + (size_t)l * CONVDIM * 4;
    const float* cb  = conv_b + (size_t)l * CONVDIM;
    const float* dtbias_l = dt_bias + (size_t)l * NHEADS;
    const float* alog_l   = A_log + (size_t)l * NHEADS;
    const float* D_l      = Dp + (size_t)l * NHEADS;
    const float* gw  = gnorm_w + (size_t)l * DINNER;
    const float* opw = out_proj_w + (size_t)l * DMODEL * DINNER;
    const float* bnw = block_norm_w + (size_t)l * DMODEL;

    cvt_weights_kernel<<<(cvt_total + 255) / 256, 256, 0, stream>>>(ipw, opw, w_in_bf, w_out_bf);
    prenorm_kernel<<<NROWS, 128, 0, stream>>>(hidden, residual, bnw, xn_bf);
    dim3 g1(DINPROJP / 128, NROWS / 128);
    gemm_bf16_bt<128><<<g1, 256, 0, stream>>>(xn_bf, w_in_bf, zx, NROWS, DINPROJ, DMODEL);
    convdt_kernel<<<NROWS, 320, 0, stream>>>(zx, cw, cb, dtbias_l, alog_l, convo, dtb, dAb);
    scan_local_kernel<<<dim3(NCH, BATCH * NHEADS), 256, 0, stream>>>(
        convo, dtb, dAb, D_l, ybuf, state, cprod);
    ycorr_kernel<<<dim3(NCH - 1, BATCH * NHEADS), 256, 0, stream>>>(
        convo, dAb, state, cprod, ybuf);
    gated_norm_kernel<<<NROWS, 256, 0, stream>>>(ybuf, zx, gw, yn_bf);
    dim3 g2(DMODEL / 64, NROWS / 128);
    gemm_bf16_bt<64><<<g2, 256, 0, stream>>>(yn_bf, w_out_bf, hidden, NROWS, DMODEL, DINNER);
  }

  prenorm_kernel<<<NROWS, 128, 0, stream>>>(hidden, residual, norm_f_w, xn_bf);
  dim3 g3(VOCABSZ / 64, NROWS / 128);
  gemm_bf16_bt<64><<<g3, 256, 0, stream>>>(xn_bf, w_emb_bf, out, NROWS, VOCABSZ, DMODEL);
  rowloss_kernel<<<NROWS / 4, 256, 0, stream>>>(out, targets, rowloss);
  loss_reduce_kernel<<<1, 256, 0, stream>>>(rowloss, out + (size_t)(out_size - 1));
}